// Round 13
// baseline (869.519 us; speedup 1.0000x reference)
//
#include <hip/hip_runtime.h>
#include <cstdint>

// Problem constants (fixed by the harness inputs)
#define NROWS 8192
#define DM    768
#define DS    16384
#define PREB_STRIDE 32768   // ushort elements: bf16 row r lives in the first
                            // half of fp32 z-row r's own 64KB span (race-free)

typedef __attribute__((ext_vector_type(8))) short          bf16x8;
typedef __attribute__((ext_vector_type(8))) unsigned short u16x8;
typedef __attribute__((ext_vector_type(4))) float          f32x4;

__device__ __forceinline__ unsigned short f2bf(float f) {
  unsigned u = __float_as_uint(f);
  unsigned r = u + 0x7fffu + ((u >> 16) & 1u);   // RNE
  return (unsigned short)(r >> 16);
}
__device__ __forceinline__ float bf2f(unsigned short us) {
  return __uint_as_float(((unsigned)us) << 16);
}

// async 16B global->LDS DMA; lds dest must be wave-uniform (HW writes
// base + lane*16), global src is per-lane (m97/m104/m173 semantics).
#define GLOAD_LDS16(g, l)                                                     \
  __builtin_amdgcn_global_load_lds(                                           \
      (const __attribute__((address_space(1))) void*)(g),                     \
      (__attribute__((address_space(3))) void*)(l), 16, 0, 0)

#define MARGIN 0.04f
// fine range: value in [2^-6, 4.0) <=> bits in [0x3C800000, 0x40800000)
#define FINE_LO 0x3C800000u
#define FINE_HI 0x40800000u
#define HICAP 256
#define BDCAP 512
#define SELCAP 160

// ======================= FAST PATH =============================================

// ---- prep 1: x fp32 -> bf16 ----
__global__ __launch_bounds__(256) void cvt_x_bf16(const float* __restrict__ x,
                                                  unsigned short* __restrict__ xb) {
  int i = blockIdx.x * 256 + threadIdx.x;        // float4 index; grid covers exactly
  float4 v = ((const float4*)x)[i];
  ushort4 o;
  o.x = f2bf(v.x); o.y = f2bf(v.y); o.z = f2bf(v.z); o.w = f2bf(v.w);
  ((ushort4*)xb)[i] = o;
}

// ---- prep 1b: W_dec fp32 -> bf16 (decode table; halves gather traffic) ----
__global__ __launch_bounds__(256) void cvt_wd_bf16(const float* __restrict__ wd,
                                                   unsigned short* __restrict__ wdb) {
  int i = blockIdx.x * 256 + threadIdx.x;        // float4 index; grid covers exactly
  float4 v = ((const float4*)wd)[i];
  ushort4 o;
  o.x = f2bf(v.x); o.y = f2bf(v.y); o.z = f2bf(v.z); o.w = f2bf(v.w);
  ((ushort4*)wdb)[i] = o;
}

// ---- prep 2: W_enc [DM][DS] -> WTf fp32 [DS][DM] + WTb bf16 [DS][DM] ----
__global__ __launch_bounds__(256) void transpose_w(const float* __restrict__ We,
                                                   float* __restrict__ WTf,
                                                   unsigned short* __restrict__ WTb) {
  __shared__ float t[32][33];
  const int c0 = blockIdx.x * 32;   // DS dim
  const int r0 = blockIdx.y * 32;   // DM dim
  const int tx = threadIdx.x & 31, ty = threadIdx.x >> 5;  // ty 0..7
#pragma unroll
  for (int i = 0; i < 4; ++i)
    t[ty + i * 8][tx] = We[(size_t)(r0 + ty + i * 8) * DS + c0 + tx];
  __syncthreads();
#pragma unroll
  for (int i = 0; i < 4; ++i) {
    float v = t[tx][ty + i * 8];
    size_t o = (size_t)(c0 + ty + i * 8) * DM + r0 + tx;
    WTf[o] = v;
    WTb[o] = f2bf(v);
  }
}

// ---- approx encode (R12, proven): preb = bf16(x@We + be) via MFMA;
//      staging via global_load_lds w=16 with pre-swizzled source; blocks with
//      n0 >= DS/2 zero the upper-half fp32 z tile (disjoint bytes).
__global__ __launch_bounds__(256) void sae_encode_bf16(
    const unsigned short* __restrict__ xb,   // [NROWS][DM] bf16
    const unsigned short* __restrict__ WTb,  // [DS][DM] bf16 (W_enc^T)
    const float* __restrict__ be,            // [DS]
    unsigned short* __restrict__ preb,       // [NROWS][PREB_STRIDE] bf16 approx
    float* __restrict__ zfull)               // fp32 z view of the same region
{
  __shared__ __align__(16) short As[128 * 64];
  __shared__ __align__(16) short Bs[128 * 64];

  const int tid  = threadIdx.x;
  const int lane = tid & 63;
  const int w    = tid >> 6;          // wave 0..3
  const int wm   = w >> 1, wn = w & 1;
  const int m0   = blockIdx.y * 128, n0 = blockIdx.x * 128;
  const int l15  = lane & 15, q = lane >> 4, l7 = lane & 7;

  f32x4 acc[4][4];
  const f32x4 zero4 = {0.f, 0.f, 0.f, 0.f};
#pragma unroll
  for (int i = 0; i < 4; ++i)
#pragma unroll
    for (int j = 0; j < 4; ++j) acc[i][j] = zero4;

  for (int k0 = 0; k0 < DM; k0 += 64) {
#pragma unroll
    for (int j = 0; j < 4; ++j) {
      int pj  = (w << 8) + (j << 6) + lane;
      int m   = pj >> 3, gp = pj & 7;
      int col = ((gp ^ (m & 7)) << 3);          // ushort offset within row
      const unsigned short* ga = xb  + (size_t)(m0 + m) * DM + k0 + col;
      const unsigned short* gb = WTb + (size_t)(n0 + m) * DM + k0 + col;
      int ldsoff = ((w << 8) + (j << 6)) << 4;  // wave-uniform byte base
      GLOAD_LDS16(ga, (char*)As + ldsoff);
      GLOAD_LDS16(gb, (char*)Bs + ldsoff);
    }
    __syncthreads();

#pragma unroll
    for (int h = 0; h < 2; ++h) {
      const int gsw = (((h * 4 + q) ^ l7) << 4);
      bf16x8 af[4], bfr[4];
#pragma unroll
      for (int t = 0; t < 4; ++t) {
        af[t]  = *(const bf16x8*)((const char*)As + (wm * 64 + t * 16 + l15) * 128 + gsw);
        bfr[t] = *(const bf16x8*)((const char*)Bs + (wn * 64 + t * 16 + l15) * 128 + gsw);
      }
#pragma unroll
      for (int mf = 0; mf < 4; ++mf)
#pragma unroll
        for (int nf = 0; nf < 4; ++nf)
          acc[mf][nf] = __builtin_amdgcn_mfma_f32_16x16x32_bf16(
              af[mf], bfr[nf], acc[mf][nf], 0, 0, 0);
    }
    __syncthreads();
  }

#pragma unroll
  for (int nf = 0; nf < 4; ++nf) {
    const int gcol = n0 + wn * 64 + nf * 16 + l15;
    const float bias = be[gcol];
#pragma unroll
    for (int mf = 0; mf < 4; ++mf) {
#pragma unroll
      for (int r = 0; r < 4; ++r) {
        int grow = m0 + wm * 64 + mf * 16 + q * 4 + r;
        preb[(size_t)grow * PREB_STRIDE + gcol] = f2bf(acc[mf][nf][r] + bias);
      }
    }
  }

  if (n0 >= DS / 2) {
    const float4 z4 = make_float4(0.f, 0.f, 0.f, 0.f);
    const int r0w = tid >> 5;            // 0..7
    const int c0w = (tid & 31) << 2;     // 0..124
#pragma unroll
    for (int i = 0; i < 16; ++i) {
      *(float4*)(zfull + (size_t)(m0 + r0w + i * 8) * DS + n0 + c0w) = z4;
    }
  }
}

// ---- shared device helper: per-row threshold from fine histogram ----
// (logic identical to R12 fused pass 1; used by both split and fused paths)

// ---- R13 kernel A: STREAM-ONLY select. hist + classify + zero; emits
//      hi/band candidate lists to workspace. No x load, no table gathers --
//      runs at stream BW without evicting WTf/WdB from L3.
__global__ __launch_bounds__(256) void sae_select2(
    float* __restrict__ z,            // z region; bf16 row r in first half of span r
    int*   __restrict__ hiIdxAll,     // [NROWS][HICAP]
    float* __restrict__ hiValAll,     // [NROWS][HICAP]
    int*   __restrict__ bdIdxAll,     // [NROWS][BDCAP]
    uint2* __restrict__ cnts,         // [NROWS] (nh_raw, nb_raw)
    const int* __restrict__ kptr)
{
  const int row = blockIdx.x;
  const int tid = threadIdx.x;
  int k = *kptr; if (k < 1) k = 1; if (k > 128) k = 128;

  float* zrow = z + (size_t)row * DS;
  const unsigned short* zrowb = (const unsigned short*)zrow;

  __shared__ int   fine[2048];
  __shared__ int   part[256];
  __shared__ int   s_above, s_pos, s_nh, s_nb;
  __shared__ uint2 sh_LU;

#pragma unroll
  for (int i = 0; i < 8; ++i) fine[tid + i * 256] = 0;
  if (tid == 0) { s_above = 0; s_pos = 0; s_nh = 0; s_nb = 0; }
  __syncthreads();

  // pass 1: read bf16 row + fine histogram
  int above_c = 0, pos_c = 0;
  {
    const u16x8* srcb = (const u16x8*)zrowb;
#pragma unroll
    for (int it = 0; it < 8; ++it) {
      int idx = tid + it * 256;
      u16x8 v = srcb[idx];
#pragma unroll
      for (int e = 0; e < 8; ++e) {
        unsigned short us = (unsigned short)v[e];
        if (us > 0 && us < 0x8000) {
          ++pos_c;
          unsigned b = ((unsigned)us) << 16;
          if (b >= FINE_HI) ++above_c;
          else if (b >= FINE_LO) atomicAdd(&fine[(b >> 15) - (FINE_LO >> 15)], 1);
        }
      }
    }
  }
  if (above_c) atomicAdd(&s_above, above_c);
  if (pos_c)   atomicAdd(&s_pos, pos_c);
  __syncthreads();

  int p = 0;
#pragma unroll
  for (int i = 0; i < 8; ++i) p += fine[tid * 8 + i];
  part[tid] = p;
  __syncthreads();
  for (int off = 1; off < 256; off <<= 1) {
    int v = part[tid];
    int add = (tid + off < 256) ? part[tid + off] : 0;
    __syncthreads();
    part[tid] = v + add;
    __syncthreads();
  }
  const int tot_fine = part[0];

  if (s_pos < k) {
    if (tid == 0) sh_LU = make_uint2(0u, 0u);
  } else if (s_above >= k) {
    if (tid == 0) sh_LU = make_uint2(FINE_HI, 0x7F7FFFFFu);
  } else if (s_above + tot_fine < k) {
    if (tid == 0) sh_LU = make_uint2(0u, FINE_LO);
  } else {
    int nxt = (tid == 255) ? 0 : part[tid + 1];
    if (s_above + part[tid] >= k && (tid == 255 || s_above + nxt < k)) {
      int acc = s_above + nxt;
      int bin = 0;
      for (int i = 7; i >= 0; --i) {
        acc += fine[tid * 8 + i];
        if (acc >= k) { bin = tid * 8 + i; break; }
      }
      unsigned L = (unsigned)(bin + (int)(FINE_LO >> 15)) << 15;
      sh_LU = make_uint2(L, L + (1u << 15));
    }
  }
  __syncthreads();

  unsigned ulo, uhi;
  {
    const uint2 t2 = sh_LU;
    if (t2.y == 0u) { ulo = 0u; uhi = 0u; }
    else {
      float Lf = __uint_as_float(t2.x) - MARGIN;
      ulo = (Lf > 0.f) ? __float_as_uint(Lf) : 0u;
      float Uf = __uint_as_float(t2.y) + MARGIN;
      uhi = __float_as_uint(Uf);
    }
  }

  int*   hiI = hiIdxAll + (size_t)row * HICAP;
  float* hiV = hiValAll + (size_t)row * HICAP;
  int*   bdI = bdIdxAll + (size_t)row * BDCAP;

  // pass 2a: classify (L3-hot re-read), lists -> workspace
  {
    const u16x8* srcb = (const u16x8*)zrowb;
#pragma unroll
    for (int it = 0; it < 8; ++it) {
      int idx = tid + it * 256;
      u16x8 v = srcb[idx];
#pragma unroll
      for (int e = 0; e < 8; ++e) {
        unsigned short us = (unsigned short)v[e];
        if (us > 0 && us < 0x8000) {
          unsigned b = ((unsigned)us) << 16;
          if (b > uhi) {
            int pp = atomicAdd(&s_nh, 1);
            if (pp < HICAP) { hiI[pp] = idx * 8 + e; hiV[pp] = __uint_as_float(b); }
          } else if (b > ulo) {
            int pp = atomicAdd(&s_nb, 1);
            if (pp < BDCAP) bdI[pp] = idx * 8 + e;
          }
        }
      }
    }
  }
  // pass 2b: zero-write fp32 cols 0..8191 (same-thread chunk ownership)
  {
    const float4 z4 = make_float4(0.f, 0.f, 0.f, 0.f);
    float4* p4 = (float4*)zrow;
#pragma unroll
    for (int jj = 0; jj < 8; ++jj) p4[tid + jj * 256] = z4;
  }
  __syncthreads();
  if (tid == 0) cnts[row] = make_uint2((unsigned)s_nh, (unsigned)s_nb);
}

// ---- R13 kernel B: GATHER-ONLY finish. Band recompute (bit-identical serial
//      fp32 chains), deterministic rank/slot-order, scatter, sparse decode.
//      No stream traffic -> WTf/WdB stay L3-resident.
__global__ __launch_bounds__(256) void sae_finish(
    float* __restrict__ z,
    float* __restrict__ recon,
    const float* __restrict__ x,
    const float* __restrict__ WTf,
    const float* __restrict__ be,
    const unsigned short* __restrict__ WdB,
    const float* __restrict__ bd,
    const int*   __restrict__ hiIdxAll,
    const float* __restrict__ hiValAll,
    const int*   __restrict__ bdIdxAll,
    const uint2* __restrict__ cnts,
    const int* __restrict__ kptr)
{
  const int row = blockIdx.x;
  const int tid = threadIdx.x;
  int k = *kptr; if (k < 1) k = 1; if (k > 128) k = 128;

  float* zrow = z + (size_t)row * DS;

  __shared__ float xs[DM];
  __shared__ int   hi_idx[HICAP];
  __shared__ float hi_val[HICAP];
  __shared__ int   bd_idx[BDCAP];
  __shared__ float cex[BDCAP];
  __shared__ int   sidx[SELCAP];
  __shared__ float sval[SELCAP];

  const uint2 c2 = cnts[row];
  const int nh = ((int)c2.x < HICAP) ? (int)c2.x : HICAP;
  const int nb = ((int)c2.y < BDCAP) ? (int)c2.y : BDCAP;

  for (int i = tid; i < DM; i += 256) xs[i] = x[(size_t)row * DM + i];
  {
    const int*   hiI = hiIdxAll + (size_t)row * HICAP;
    const float* hiV = hiValAll + (size_t)row * HICAP;
    const int*   bdI = bdIdxAll + (size_t)row * BDCAP;
    for (int i = tid; i < nh; i += 256) { hi_idx[i] = hiI[i]; hi_val[i] = hiV[i]; }
    for (int i = tid; i < nb; i += 256) { bd_idx[i] = bdI[i]; }
  }
  __syncthreads();

  // exact fp32 recompute for band -- IDENTICAL arithmetic to R2/R4-R12:
  // serial k=0..767 fmaf chain, then +bias; relu at ranking.
  for (int c = tid; c < nb; c += 256) {
    const float* wcol = WTf + (size_t)bd_idx[c] * DM;
    float s = 0.f;
#pragma unroll 8
    for (int i = 0; i < DM; ++i) s = fmaf(xs[i], wcol[i], s);
    cex[c] = s + be[bd_idx[c]];
  }
  __syncthreads();

  int nh_kept, need;
  if (nh <= k) {
    nh_kept = nh;
    need = k - nh;
    for (int t = tid; t < nh; t += 256) {
      int myi = hi_idx[t];
      int r = 0;
      for (int c = 0; c < nh; ++c) r += (hi_idx[c] < myi);
      sidx[r] = myi; sval[r] = hi_val[t];
    }
  } else {
    nh_kept = k;
    need = 0;
    for (int t = tid; t < nh; t += 256) {
      float er = hi_val[t];
      int myi = hi_idx[t];
      int r = 0;
      for (int c = 0; c < nh; ++c)
        r += (hi_val[c] > er) || (hi_val[c] == er && hi_idx[c] < myi);
      if (r < k) { sidx[r] = myi; sval[r] = er; }
    }
  }
  __syncthreads();

  for (int t = tid; t < nb; t += 256) {
    float er = fmaxf(cex[t], 0.f);
    int myi = bd_idx[t];
    int r = 0;
    for (int c = 0; c < nb; ++c) {
      float ec = fmaxf(cex[c], 0.f);
      r += (ec > er) || (ec == er && bd_idx[c] < myi);
    }
    if (r < need) { sidx[nh_kept + r] = myi; sval[nh_kept + r] = er; }
  }
  __syncthreads();

  const int nsel = nh_kept + (need < nb ? need : nb);

  if (tid < nsel) zrow[sidx[tid]] = sval[tid];

  float a0 = bd[tid], a1 = bd[tid + 256], a2 = bd[tid + 512];
  for (int r = 0; r < nsel; ++r) {
    float v = sval[r];
    const unsigned short* wr = WdB + (size_t)sidx[r] * DM;
    a0 = fmaf(v, bf2f(wr[tid]),       a0);
    a1 = fmaf(v, bf2f(wr[tid + 256]), a1);
    a2 = fmaf(v, bf2f(wr[tid + 512]), a2);
  }
  float* rr = recon + (size_t)row * DM;
  rr[tid] = a0; rr[tid + 256] = a1; rr[tid + 512] = a2;
}

// ---- R12 fused (proven) -- mid-tier fallback when ws lacks list space ----
__global__ __launch_bounds__(256) void sae_topk_fused(
    float* __restrict__ z, float* __restrict__ recon,
    const float* __restrict__ x, const float* __restrict__ WTf,
    const float* __restrict__ be, const float* __restrict__ Wd,
    const unsigned short* __restrict__ WdB, const float* __restrict__ bd,
    const int* __restrict__ kptr)
{
  const int row = blockIdx.x;
  const int tid = threadIdx.x;
  int k = *kptr; if (k < 1) k = 1; if (k > 128) k = 128;

  float* zrow = z + (size_t)row * DS;
  const unsigned short* zrowb = (const unsigned short*)zrow;

  __shared__ int   fine[2048];
  __shared__ int   part[256];
  __shared__ int   s_above, s_pos;
  __shared__ uint2 sh_LU;
  __shared__ float xs[DM];
  __shared__ int   hi_idx[HICAP];
  __shared__ float hi_val[HICAP];
  __shared__ int   bd_idx[BDCAP];
  __shared__ float cex[BDCAP];
  __shared__ int   s_nh, s_nb;
  __shared__ int   sidx[SELCAP];
  __shared__ float sval[SELCAP];

#pragma unroll
  for (int i = 0; i < 8; ++i) fine[tid + i * 256] = 0;
  if (tid == 0) { s_above = 0; s_pos = 0; s_nh = 0; s_nb = 0; }
  for (int i = tid; i < DM; i += 256) xs[i] = x[(size_t)row * DM + i];
  __syncthreads();

  int above_c = 0, pos_c = 0;
  {
    const u16x8* srcb = (const u16x8*)zrowb;
#pragma unroll
    for (int it = 0; it < 8; ++it) {
      int idx = tid + it * 256;
      u16x8 v = srcb[idx];
#pragma unroll
      for (int e = 0; e < 8; ++e) {
        unsigned short us = (unsigned short)v[e];
        if (us > 0 && us < 0x8000) {
          ++pos_c;
          unsigned b = ((unsigned)us) << 16;
          if (b >= FINE_HI) ++above_c;
          else if (b >= FINE_LO) atomicAdd(&fine[(b >> 15) - (FINE_LO >> 15)], 1);
        }
      }
    }
  }
  if (above_c) atomicAdd(&s_above, above_c);
  if (pos_c)   atomicAdd(&s_pos, pos_c);
  __syncthreads();

  int p = 0;
#pragma unroll
  for (int i = 0; i < 8; ++i) p += fine[tid * 8 + i];
  part[tid] = p;
  __syncthreads();
  for (int off = 1; off < 256; off <<= 1) {
    int v = part[tid];
    int add = (tid + off < 256) ? part[tid + off] : 0;
    __syncthreads();
    part[tid] = v + add;
    __syncthreads();
  }
  const int tot_fine = part[0];

  if (s_pos < k) {
    if (tid == 0) sh_LU = make_uint2(0u, 0u);
  } else if (s_above >= k) {
    if (tid == 0) sh_LU = make_uint2(FINE_HI, 0x7F7FFFFFu);
  } else if (s_above + tot_fine < k) {
    if (tid == 0) sh_LU = make_uint2(0u, FINE_LO);
  } else {
    int nxt = (tid == 255) ? 0 : part[tid + 1];
    if (s_above + part[tid] >= k && (tid == 255 || s_above + nxt < k)) {
      int acc = s_above + nxt;
      int bin = 0;
      for (int i = 7; i >= 0; --i) {
        acc += fine[tid * 8 + i];
        if (acc >= k) { bin = tid * 8 + i; break; }
      }
      unsigned L = (unsigned)(bin + (int)(FINE_LO >> 15)) << 15;
      sh_LU = make_uint2(L, L + (1u << 15));
    }
  }
  __syncthreads();

  unsigned ulo, uhi;
  {
    const uint2 t2 = sh_LU;
    if (t2.y == 0u) { ulo = 0u; uhi = 0u; }
    else {
      float Lf = __uint_as_float(t2.x) - MARGIN;
      ulo = (Lf > 0.f) ? __float_as_uint(Lf) : 0u;
      float Uf = __uint_as_float(t2.y) + MARGIN;
      uhi = __float_as_uint(Uf);
    }
  }

  {
    const u16x8* srcb = (const u16x8*)zrowb;
#pragma unroll
    for (int it = 0; it < 8; ++it) {
      int idx = tid + it * 256;
      u16x8 v = srcb[idx];
#pragma unroll
      for (int e = 0; e < 8; ++e) {
        unsigned short us = (unsigned short)v[e];
        if (us > 0 && us < 0x8000) {
          unsigned b = ((unsigned)us) << 16;
          if (b > uhi) {
            int pp = atomicAdd(&s_nh, 1);
            if (pp < HICAP) { hi_idx[pp] = idx * 8 + e; hi_val[pp] = __uint_as_float(b); }
          } else if (b > ulo) {
            int pp = atomicAdd(&s_nb, 1);
            if (pp < BDCAP) bd_idx[pp] = idx * 8 + e;
          }
        }
      }
    }
  }
  {
    const float4 z4 = make_float4(0.f, 0.f, 0.f, 0.f);
    float4* p4 = (float4*)zrow;
#pragma unroll
    for (int jj = 0; jj < 8; ++jj) p4[tid + jj * 256] = z4;
  }
  __syncthreads();
  const int nh = (s_nh < HICAP) ? s_nh : HICAP;
  const int nb = (s_nb < BDCAP) ? s_nb : BDCAP;

  for (int c = tid; c < nb; c += 256) {
    const float* wcol = WTf + (size_t)bd_idx[c] * DM;
    float s = 0.f;
#pragma unroll 8
    for (int i = 0; i < DM; ++i) s = fmaf(xs[i], wcol[i], s);
    cex[c] = s + be[bd_idx[c]];
  }
  __syncthreads();

  int nh_kept, need;
  if (nh <= k) {
    nh_kept = nh;
    need = k - nh;
    for (int t = tid; t < nh; t += 256) {
      int myi = hi_idx[t];
      int r = 0;
      for (int c = 0; c < nh; ++c) r += (hi_idx[c] < myi);
      sidx[r] = myi; sval[r] = hi_val[t];
    }
  } else {
    nh_kept = k;
    need = 0;
    for (int t = tid; t < nh; t += 256) {
      float er = hi_val[t];
      int myi = hi_idx[t];
      int r = 0;
      for (int c = 0; c < nh; ++c)
        r += (hi_val[c] > er) || (hi_val[c] == er && hi_idx[c] < myi);
      if (r < k) { sidx[r] = myi; sval[r] = er; }
    }
  }
  __syncthreads();

  for (int t = tid; t < nb; t += 256) {
    float er = fmaxf(cex[t], 0.f);
    int myi = bd_idx[t];
    int r = 0;
    for (int c = 0; c < nb; ++c) {
      float ec = fmaxf(cex[c], 0.f);
      r += (ec > er) || (ec == er && bd_idx[c] < myi);
    }
    if (r < need) { sidx[nh_kept + r] = myi; sval[nh_kept + r] = er; }
  }
  __syncthreads();

  const int nsel = nh_kept + (need < nb ? need : nb);
  if (tid < nsel) zrow[sidx[tid]] = sval[tid];

  float a0 = bd[tid], a1 = bd[tid + 256], a2 = bd[tid + 512];
  if (WdB) {
    for (int r = 0; r < nsel; ++r) {
      float v = sval[r];
      const unsigned short* wr = WdB + (size_t)sidx[r] * DM;
      a0 = fmaf(v, bf2f(wr[tid]),       a0);
      a1 = fmaf(v, bf2f(wr[tid + 256]), a1);
      a2 = fmaf(v, bf2f(wr[tid + 512]), a2);
    }
  } else {
    for (int r = 0; r < nsel; ++r) {
      float v = sval[r];
      const float* wr = Wd + (size_t)sidx[r] * DM;
      a0 = fmaf(v, wr[tid],       a0);
      a1 = fmaf(v, wr[tid + 256], a1);
      a2 = fmaf(v, wr[tid + 512], a2);
    }
  }
  float* rr = recon + (size_t)row * DM;
  rr[tid] = a0; rr[tid + 256] = a1; rr[tid + 512] = a2;
}

// ======================= FALLBACK PATH (R2, proven) =======================
#define BM 128
#define BN 128
#define BK 32

__global__ __launch_bounds__(256) void sae_encode_gemm(
    const float* __restrict__ x, const float* __restrict__ We,
    const float* __restrict__ be, float* __restrict__ pre)
{
  __shared__ float As2[BK][BM];
  __shared__ float Bs2[BK][BN];

  const int tid = threadIdx.x;
  const int bx  = blockIdx.x;
  const int by  = blockIdx.y;
  const int c0  = (tid & 15) * 4;
  const int r0  = (tid >> 4) * 4;

  float acc[2][2][4][4];
#pragma unroll
  for (int p = 0; p < 2; ++p)
#pragma unroll
    for (int qq = 0; qq < 2; ++qq)
#pragma unroll
      for (int i = 0; i < 4; ++i)
#pragma unroll
        for (int j = 0; j < 4; ++j) acc[p][qq][i][j] = 0.f;

  const float* xblk = x  + (size_t)by * BM * DM;
  const float* wblk = We + (size_t)bx * BN;

  for (int k0 = 0; k0 < DM; k0 += BK) {
#pragma unroll
    for (int i = 0; i < 4; ++i) {
      int s  = tid + i * 256;
      int m  = s >> 3;
      int kk4 = (s & 7) << 2;
      float4 v = *(const float4*)(xblk + (size_t)m * DM + (k0 + kk4));
      int cs = m ^ kk4;
      As2[kk4 + 0][cs] = v.x;
      As2[kk4 + 1][cs] = v.y;
      As2[kk4 + 2][cs] = v.z;
      As2[kk4 + 3][cs] = v.w;
    }
#pragma unroll
    for (int i = 0; i < 4; ++i) {
      int s  = tid + i * 256;
      int kk = s >> 5;
      int n  = (s & 31) << 2;
      *(float4*)&Bs2[kk][n] = *(const float4*)(wblk + (size_t)(k0 + kk) * DS + n);
    }
    __syncthreads();
#pragma unroll 4
    for (int kk = 0; kk < BK; ++kk) {
      const int kkm = kk & 0x1C;
      const int ra  = r0 ^ kkm;
      float4 a0 = *(const float4*)&As2[kk][ra];
      float4 a1 = *(const float4*)&As2[kk][ra + 64];
      float4 b0 = *(const float4*)&Bs2[kk][c0];
      float4 b1 = *(const float4*)&Bs2[kk][c0 + 64];
      float av[2][4] = {{a0.x, a0.y, a0.z, a0.w}, {a1.x, a1.y, a1.z, a1.w}};
      float bv[2][4] = {{b0.x, b0.y, b0.z, b0.w}, {b1.x, b1.y, b1.z, b1.w}};
#pragma unroll
      for (int p = 0; p < 2; ++p)
#pragma unroll
        for (int qq = 0; qq < 2; ++qq)
#pragma unroll
          for (int i = 0; i < 4; ++i)
#pragma unroll
            for (int j = 0; j < 4; ++j)
              acc[p][qq][i][j] = fmaf(av[p][i], bv[qq][j], acc[p][qq][i][j]);
    }
    __syncthreads();
  }

  const int row0 = by * BM + r0;
  const int col0 = bx * BN + c0;
  float bias[2][4];
#pragma unroll
  for (int qq = 0; qq < 2; ++qq)
#pragma unroll
    for (int j = 0; j < 4; ++j) bias[qq][j] = be[col0 + qq * 64 + j];
#pragma unroll
  for (int p = 0; p < 2; ++p)
#pragma unroll
    for (int i = 0; i < 4; ++i) {
      float* dst = pre + (size_t)(row0 + p * 64 + i) * DS + col0;
#pragma unroll
      for (int qq = 0; qq < 2; ++qq) {
        float4 o;
        o.x = fmaxf(acc[p][qq][i][0] + bias[qq][0], 0.f);
        o.y = fmaxf(acc[p][qq][i][1] + bias[qq][1], 0.f);
        o.z = fmaxf(acc[p][qq][i][2] + bias[qq][2], 0.f);
        o.w = fmaxf(acc[p][qq][i][3] + bias[qq][3], 0.f);
        *(float4*)(dst + qq * 64) = o;
      }
    }
}

__global__ __launch_bounds__(256) void sae_topk_decode(
    float* __restrict__ z, float* __restrict__ recon,
    const float* __restrict__ Wd, const float* __restrict__ bd,
    const int* __restrict__ kptr)
{
  const int row = blockIdx.x;
  const int tid = threadIdx.x;
  int k = *kptr;
  if (k < 1) k = 1;
  if (k > 1024) k = 1024;

  float* zrow = z + (size_t)row * DS;

  unsigned u[64];
  {
    const float4* src = (const float4*)zrow;
#pragma unroll
    for (int jj = 0; jj < 16; ++jj) {
      float4 v = src[tid + jj * 256];
      u[jj * 4 + 0] = (v.x > 0.f) ? __float_as_uint(v.x) : 0u;
      u[jj * 4 + 1] = (v.y > 0.f) ? __float_as_uint(v.y) : 0u;
      u[jj * 4 + 2] = (v.z > 0.f) ? __float_as_uint(v.z) : 0u;
      u[jj * 4 + 3] = (v.w > 0.f) ? __float_as_uint(v.w) : 0u;
    }
  }

  __shared__ int red[8];
  unsigned tbits = 0;
  for (int bit = 30; bit >= 0; --bit) {
    unsigned cand = tbits | (1u << bit);
    int c = 0;
#pragma unroll
    for (int j = 0; j < 64; ++j) c += (u[j] >= cand);
#pragma unroll
    for (int off = 32; off > 0; off >>= 1) c += __shfl_down(c, off, 64);
    if ((tid & 63) == 0) red[tid >> 6] = c;
    __syncthreads();
    int tot = red[0] + red[1] + red[2] + red[3];
    __syncthreads();
    if (tot >= k) tbits = cand;
  }

  int cnt_gt = 0, cnt_eq = 0;
  if (tbits != 0) {
    int c1 = 0, c2 = 0;
#pragma unroll
    for (int j = 0; j < 64; ++j) { c1 += (u[j] > tbits); c2 += (u[j] == tbits); }
#pragma unroll
    for (int off = 32; off > 0; off >>= 1) {
      c1 += __shfl_down(c1, off, 64);
      c2 += __shfl_down(c2, off, 64);
    }
    if ((tid & 63) == 0) { red[tid >> 6] = c1; red[4 + (tid >> 6)] = c2; }
    __syncthreads();
    cnt_gt = red[0] + red[1] + red[2] + red[3];
    cnt_eq = red[4] + red[5] + red[6] + red[7];
    __syncthreads();
  }
  const int needed = k - cnt_gt;

  __shared__ int eq_n;
  __shared__ int eq_keep;
  __shared__ int eq_idx[256];
  const bool rare = (tbits != 0) && (cnt_eq > needed);
  if (rare) {
    if (tid == 0) eq_n = 0;
    __syncthreads();
#pragma unroll
    for (int jj = 0; jj < 16; ++jj)
#pragma unroll
      for (int c = 0; c < 4; ++c) {
        int j = jj * 4 + c;
        if (u[j] == tbits) {
          int p = atomicAdd(&eq_n, 1);
          if (p < 256) eq_idx[p] = (tid + jj * 256) * 4 + c;
        }
      }
    __syncthreads();
    if (tid == 0) {
      int n = eq_n < 256 ? eq_n : 256;
      for (int a = 1; a < n; ++a) {
        int key = eq_idx[a]; int b = a - 1;
        while (b >= 0 && eq_idx[b] > key) { eq_idx[b + 1] = eq_idx[b]; --b; }
        eq_idx[b + 1] = key;
      }
      int kp = needed < n ? needed : n;
      eq_keep = kp < 0 ? 0 : kp;
    }
    __syncthreads();
  }

  unsigned long long mask = 0ull;
#pragma unroll
  for (int jj = 0; jj < 16; ++jj)
#pragma unroll
    for (int c = 0; c < 4; ++c) {
      int j = jj * 4 + c;
      bool s;
      if (tbits == 0) {
        s = (u[j] > 0u);
      } else if (u[j] > tbits) {
        s = true;
      } else if (u[j] == tbits) {
        if (!rare) s = true;
        else {
          int idx = (tid + jj * 256) * 4 + c;
          s = false;
          for (int e = 0; e < eq_keep; ++e)
            if (eq_idx[e] == idx) { s = true; break; }
        }
      } else s = false;
      if (s) mask |= (1ull << j);
    }
  const int mycount = __popcll(mask);

  __shared__ int scan[256];
  scan[tid] = mycount;
  __syncthreads();
  for (int off = 1; off < 256; off <<= 1) {
    int v = scan[tid];
    int add = (tid >= off) ? scan[tid - off] : 0;
    __syncthreads();
    scan[tid] = v + add;
    __syncthreads();
  }
  const int total = scan[255];
  int pos = scan[tid] - mycount;

  __shared__ float s_val[1024];
  __shared__ int   s_idx[1024];
  {
    float4* dst = (float4*)zrow;
#pragma unroll
    for (int jj = 0; jj < 16; ++jj) {
      float4 wv;
      float* wp = (float*)&wv;
#pragma unroll
      for (int c = 0; c < 4; ++c) {
        int j = jj * 4 + c;
        bool s = (mask >> j) & 1ull;
        float val = __uint_as_float(u[j]);
        wp[c] = s ? val : 0.f;
        if (s && pos < 1024) {
          s_idx[pos] = (tid + jj * 256) * 4 + c;
          s_val[pos] = val;
          ++pos;
        }
      }
      dst[tid + jj * 256] = wv;
    }
  }
  __syncthreads();

  float a0 = bd[tid], a1 = bd[tid + 256], a2 = bd[tid + 512];
  const int n = total < 1024 ? total : 1024;
#pragma unroll 4
  for (int i = 0; i < n; ++i) {
    float v = s_val[i];
    const float* wr = Wd + (size_t)s_idx[i] * DM;
    a0 = fmaf(v, wr[tid],       a0);
    a1 = fmaf(v, wr[tid + 256], a1);
    a2 = fmaf(v, wr[tid + 512], a2);
  }
  float* rr = recon + (size_t)row * DM;
  rr[tid] = a0; rr[tid + 256] = a1; rr[tid + 512] = a2;
}

// ------------------------------------------------------------------------------
extern "C" void kernel_launch(void* const* d_in, const int* in_sizes, int n_in,
                              void* d_out, int out_size, void* d_ws, size_t ws_size,
                              hipStream_t stream) {
  (void)in_sizes; (void)n_in; (void)out_size;

  const float* x     = (const float*)d_in[0];
  const float* W_enc = (const float*)d_in[1];
  const float* b_enc = (const float*)d_in[2];
  const float* W_dec = (const float*)d_in[3];
  const float* b_dec = (const float*)d_in[4];
  const int*   kp    = (const int*)d_in[5];

  float* z     = (float*)d_out;                    // [NROWS][DS]
  float* recon = z + (size_t)NROWS * DS;           // [NROWS][DM]

  const size_t sz_WTf  = (size_t)DS * DM * 4;      // 50,331,648
  const size_t sz_WTb  = (size_t)DS * DM * 2;      // 25,165,824
  const size_t sz_xb   = (size_t)NROWS * DM * 2;   // 12,582,912
  const size_t sz_WdB  = (size_t)DS * DM * 2;      // 25,165,824
  const size_t sz_hiI  = (size_t)NROWS * HICAP * 4;  //  8,388,608
  const size_t sz_hiV  = (size_t)NROWS * HICAP * 4;  //  8,388,608
  const size_t sz_bdI  = (size_t)NROWS * BDCAP * 4;  // 16,777,216
  const size_t sz_cnt  = (size_t)NROWS * 8;          //     65,536
  const size_t need_small = sz_WTf + sz_WTb + sz_xb;             //  88 MB
  const size_t need_big   = need_small + sz_WdB;                 // 113 MB
  const size_t need_lists = need_big + sz_hiI + sz_hiV + sz_bdI + sz_cnt; // ~147 MB

  if (ws_size >= need_small) {
    float*          WTf = (float*)d_ws;
    unsigned short* WTb = (unsigned short*)((char*)d_ws + sz_WTf);
    unsigned short* xb  = (unsigned short*)((char*)d_ws + sz_WTf + sz_WTb);
    unsigned short* WdB = nullptr;

    cvt_x_bf16<<<(NROWS * DM) / (4 * 256), 256, 0, stream>>>(x, xb);
    if (ws_size >= need_big) {
      WdB = (unsigned short*)((char*)d_ws + need_small);
      cvt_wd_bf16<<<((size_t)DS * DM) / (4 * 256), 256, 0, stream>>>(W_dec, WdB);
    }
    transpose_w<<<dim3(DS / 32, DM / 32), 256, 0, stream>>>(W_enc, WTf, WTb);
    sae_encode_bf16<<<dim3(DS / 128, NROWS / 128), 256, 0, stream>>>(
        xb, WTb, b_enc, (unsigned short*)z, z);

    if (ws_size >= need_lists) {
      int*   hiI = (int*)((char*)d_ws + need_big);
      float* hiV = (float*)((char*)d_ws + need_big + sz_hiI);
      int*   bdI = (int*)((char*)d_ws + need_big + sz_hiI + sz_hiV);
      uint2* cnt = (uint2*)((char*)d_ws + need_big + sz_hiI + sz_hiV + sz_bdI);
      sae_select2<<<NROWS, 256, 0, stream>>>(z, hiI, hiV, bdI, cnt, kp);
      sae_finish<<<NROWS, 256, 0, stream>>>(z, recon, x, WTf, b_enc, WdB, b_dec,
                                            hiI, hiV, bdI, cnt, kp);
    } else {
      sae_topk_fused<<<NROWS, 256, 0, stream>>>(z, recon, x, WTf, b_enc,
                                                W_dec, WdB, b_dec, kp);
    }
  } else {
    sae_encode_gemm<<<dim3(DS / BN, NROWS / BM), 256, 0, stream>>>(x, W_enc, b_enc, z);
    sae_topk_decode<<<NROWS, 256, 0, stream>>>(z, recon, W_dec, b_dec, kp);
  }
}

// Round 14
// 843.392 us; speedup vs baseline: 1.0310x; 1.0310x over previous
//
#include <hip/hip_runtime.h>
#include <cstdint>

// Problem constants (fixed by the harness inputs)
#define NROWS 8192
#define DM    768
#define DS    16384
#define PREB_STRIDE 32768   // ushort elements: bf16 row r lives in the first
                            // half of fp32 z-row r's own 64KB span (race-free)

typedef __attribute__((ext_vector_type(8))) short          bf16x8;
typedef __attribute__((ext_vector_type(8))) unsigned short u16x8;
typedef __attribute__((ext_vector_type(4))) float          f32x4;

__device__ __forceinline__ unsigned short f2bf(float f) {
  unsigned u = __float_as_uint(f);
  unsigned r = u + 0x7fffu + ((u >> 16) & 1u);   // RNE
  return (unsigned short)(r >> 16);
}
__device__ __forceinline__ float bf2f(unsigned short us) {
  return __uint_as_float(((unsigned)us) << 16);
}

// async 16B global->LDS DMA; lds dest must be wave-uniform (HW writes
// base + lane*16), global src is per-lane (m97/m104/m173 semantics).
#define GLOAD_LDS16(g, l)                                                     \
  __builtin_amdgcn_global_load_lds(                                           \
      (const __attribute__((address_space(1))) void*)(g),                     \
      (__attribute__((address_space(3))) void*)(l), 16, 0, 0)

#define MARGIN 0.04f
// fine range: value in [2^-6, 4.0) <=> bits in [0x3C800000, 0x40800000)
#define FINE_LO 0x3C800000u
#define FINE_HI 0x40800000u
#define HICAP 256
#define BDCAP 512
#define SELCAP 160

// ======================= FAST PATH (needs ~88/113MB workspace) =================

// ---- prep 1: x fp32 -> bf16 ----
__global__ __launch_bounds__(256) void cvt_x_bf16(const float* __restrict__ x,
                                                  unsigned short* __restrict__ xb) {
  int i = blockIdx.x * 256 + threadIdx.x;        // float4 index; grid covers exactly
  float4 v = ((const float4*)x)[i];
  ushort4 o;
  o.x = f2bf(v.x); o.y = f2bf(v.y); o.z = f2bf(v.z); o.w = f2bf(v.w);
  ((ushort4*)xb)[i] = o;
}

// ---- prep 1b: W_dec fp32 -> bf16 (decode table; halves gather traffic) ----
__global__ __launch_bounds__(256) void cvt_wd_bf16(const float* __restrict__ wd,
                                                   unsigned short* __restrict__ wdb) {
  int i = blockIdx.x * 256 + threadIdx.x;        // float4 index; grid covers exactly
  float4 v = ((const float4*)wd)[i];
  ushort4 o;
  o.x = f2bf(v.x); o.y = f2bf(v.y); o.z = f2bf(v.z); o.w = f2bf(v.w);
  ((ushort4*)wdb)[i] = o;
}

// ---- prep 2: W_enc [DM][DS] -> WTf fp32 [DS][DM] + WTb bf16 [DS][DM] ----
__global__ __launch_bounds__(256) void transpose_w(const float* __restrict__ We,
                                                   float* __restrict__ WTf,
                                                   unsigned short* __restrict__ WTb) {
  __shared__ float t[32][33];
  const int c0 = blockIdx.x * 32;   // DS dim
  const int r0 = blockIdx.y * 32;   // DM dim
  const int tx = threadIdx.x & 31, ty = threadIdx.x >> 5;  // ty 0..7
#pragma unroll
  for (int i = 0; i < 4; ++i)
    t[ty + i * 8][tx] = We[(size_t)(r0 + ty + i * 8) * DS + c0 + tx];
  __syncthreads();
#pragma unroll
  for (int i = 0; i < 4; ++i) {
    float v = t[tx][ty + i * 8];
    size_t o = (size_t)(c0 + ty + i * 8) * DM + r0 + tx;
    WTf[o] = v;
    WTb[o] = f2bf(v);
  }
}

// ---- approx encode: preb = bf16(x@We + be) via MFMA (RAW, no relu) ----
// R14: 2-phase double-buffered staging (T3 minimum recipe): issue next
// K-tile's global_load_lds BEFORE computing the current tile; ONE barrier
// per K-step (its implicit vmcnt(0) drains the prefetch). Buffer-reuse safe:
// all reads of buf[cur] finish before the end-of-iter barrier, and buf[cur]
// is only re-staged after it. LDS 64KB -> 2 blocks/CU (same as measured
// effective occupancy, so no loss). MFMA core/epilogue/zero-fill unchanged.
__global__ __launch_bounds__(256) void sae_encode_bf16(
    const unsigned short* __restrict__ xb,   // [NROWS][DM] bf16
    const unsigned short* __restrict__ WTb,  // [DS][DM] bf16 (W_enc^T)
    const float* __restrict__ be,            // [DS]
    unsigned short* __restrict__ preb,       // [NROWS][PREB_STRIDE] bf16 approx
    float* __restrict__ zfull)               // fp32 z view of the same region
{
  __shared__ __align__(16) short As[2][128 * 64];
  __shared__ __align__(16) short Bs[2][128 * 64];

  const int tid  = threadIdx.x;
  const int lane = tid & 63;
  const int w    = tid >> 6;          // wave 0..3
  const int wm   = w >> 1, wn = w & 1;
  const int m0   = blockIdx.y * 128, n0 = blockIdx.x * 128;
  const int l15  = lane & 15, q = lane >> 4, l7 = lane & 7;

  f32x4 acc[4][4];
  const f32x4 zero4 = {0.f, 0.f, 0.f, 0.f};
#pragma unroll
  for (int i = 0; i < 4; ++i)
#pragma unroll
    for (int j = 0; j < 4; ++j) acc[i][j] = zero4;

  // stage one 128x64 A/B tile pair into buffer `buf` (pre-swizzled source,
  // linear wave-uniform LDS dest -- proven R12 pattern)
  auto stage = [&](int buf, int k0) {
#pragma unroll
    for (int j = 0; j < 4; ++j) {
      int pj  = (w << 8) + (j << 6) + lane;
      int m   = pj >> 3, gp = pj & 7;
      int col = ((gp ^ (m & 7)) << 3);          // ushort offset within row
      const unsigned short* ga = xb  + (size_t)(m0 + m) * DM + k0 + col;
      const unsigned short* gb = WTb + (size_t)(n0 + m) * DM + k0 + col;
      int ldsoff = ((w << 8) + (j << 6)) << 4;  // wave-uniform byte base
      GLOAD_LDS16(ga, (char*)As[buf] + ldsoff);
      GLOAD_LDS16(gb, (char*)Bs[buf] + ldsoff);
    }
  };

  stage(0, 0);
  __syncthreads();                      // buf0 ready (barrier drains vmcnt)

  int cur = 0;
  const int NT = DM / 64;               // 12 K-steps
  for (int t = 0; t < NT; ++t) {
    if (t + 1 < NT) stage(cur ^ 1, (t + 1) * 64);   // prefetch next tile

    const char* Ab = (const char*)As[cur];
    const char* Bb = (const char*)Bs[cur];
#pragma unroll
    for (int h = 0; h < 2; ++h) {
      const int gsw = (((h * 4 + q) ^ l7) << 4);
      bf16x8 af[4], bfr[4];
#pragma unroll
      for (int tt = 0; tt < 4; ++tt) {
        af[tt]  = *(const bf16x8*)(Ab + (wm * 64 + tt * 16 + l15) * 128 + gsw);
        bfr[tt] = *(const bf16x8*)(Bb + (wn * 64 + tt * 16 + l15) * 128 + gsw);
      }
#pragma unroll
      for (int mf = 0; mf < 4; ++mf)
#pragma unroll
        for (int nf = 0; nf < 4; ++nf)
          acc[mf][nf] = __builtin_amdgcn_mfma_f32_16x16x32_bf16(
              af[mf], bfr[nf], acc[mf][nf], 0, 0, 0);
    }
    __syncthreads();   // drains prefetch (vmcnt0) + guards buf reuse
    cur ^= 1;
  }

#pragma unroll
  for (int nf = 0; nf < 4; ++nf) {
    const int gcol = n0 + wn * 64 + nf * 16 + l15;
    const float bias = be[gcol];
#pragma unroll
    for (int mf = 0; mf < 4; ++mf) {
#pragma unroll
      for (int r = 0; r < 4; ++r) {
        int grow = m0 + wm * 64 + mf * 16 + q * 4 + r;
        preb[(size_t)grow * PREB_STRIDE + gcol] = f2bf(acc[mf][nf][r] + bias);
      }
    }
  }

  // zero the fp32 z tile for columns >= DS/2 (bytes disjoint from all
  // bf16 writes). Fire-and-forget stores, hidden under the MFMA-bound kernel.
  if (n0 >= DS / 2) {
    const float4 z4 = make_float4(0.f, 0.f, 0.f, 0.f);
    const int r0w = tid >> 5;            // 0..7
    const int c0w = (tid & 31) << 2;     // 0..124
#pragma unroll
    for (int i = 0; i < 16; ++i) {
      *(float4*)(zfull + (size_t)(m0 + r0w + i * 8) * DS + n0 + c0w) = z4;
    }
  }
}

// ---- FUSED select+exact (R12, proven; unchanged) ----
__global__ __launch_bounds__(256) void sae_topk_fused(
    float* __restrict__ z,            // z region; bf16 row r in first half of span r
    float* __restrict__ recon,        // [NROWS][DM]
    const float* __restrict__ x,      // fp32 [NROWS][DM]
    const float* __restrict__ WTf,    // fp32 [DS][DM] (W_enc^T)
    const float* __restrict__ be,     // [DS]
    const float* __restrict__ Wd,     // [DS][DM] fp32
    const unsigned short* __restrict__ WdB,  // [DS][DM] bf16 copy (or nullptr)
    const float* __restrict__ bd,     // [DM]
    const int* __restrict__ kptr)
{
  const int row = blockIdx.x;
  const int tid = threadIdx.x;
  int k = *kptr; if (k < 1) k = 1; if (k > 128) k = 128;  // harness k = 64

  float* zrow = z + (size_t)row * DS;
  const unsigned short* zrowb = (const unsigned short*)zrow;  // bf16 alias, same span

  __shared__ int   fine[2048];
  __shared__ int   part[256];
  __shared__ int   s_above, s_pos;
  __shared__ uint2 sh_LU;
  __shared__ float xs[DM];
  __shared__ int   hi_idx[HICAP];
  __shared__ float hi_val[HICAP];
  __shared__ int   bd_idx[BDCAP];
  __shared__ float cex[BDCAP];
  __shared__ int   s_nh, s_nb;
  __shared__ int   sidx[SELCAP];
  __shared__ float sval[SELCAP];

#pragma unroll
  for (int i = 0; i < 8; ++i) fine[tid + i * 256] = 0;
  if (tid == 0) { s_above = 0; s_pos = 0; s_nh = 0; s_nb = 0; }
  for (int i = tid; i < DM; i += 256) xs[i] = x[(size_t)row * DM + i];
  __syncthreads();

  // ---- pass 1: read bf16 row + fine histogram ----
  int above_c = 0, pos_c = 0;
  {
    const u16x8* srcb = (const u16x8*)zrowb;
#pragma unroll
    for (int it = 0; it < 8; ++it) {
      int idx = tid + it * 256;                 // 16B chunk index (2048 total)
      u16x8 v = srcb[idx];
#pragma unroll
      for (int e = 0; e < 8; ++e) {
        unsigned short us = (unsigned short)v[e];
        if (us > 0 && us < 0x8000) {            // positive bf16
          ++pos_c;
          unsigned b = ((unsigned)us) << 16;
          if (b >= FINE_HI) ++above_c;
          else if (b >= FINE_LO) atomicAdd(&fine[(b >> 15) - (FINE_LO >> 15)], 1);
        }
      }
    }
  }
  if (above_c) atomicAdd(&s_above, above_c);
  if (pos_c)   atomicAdd(&s_pos, pos_c);
  __syncthreads();

  // suffix (from-top) inclusive scan over 256 groups of 8 bins
  int p = 0;
#pragma unroll
  for (int i = 0; i < 8; ++i) p += fine[tid * 8 + i];
  part[tid] = p;
  __syncthreads();
  for (int off = 1; off < 256; off <<= 1) {
    int v = part[tid];
    int add = (tid + off < 256) ? part[tid + off] : 0;
    __syncthreads();
    part[tid] = v + add;
    __syncthreads();
  }
  const int tot_fine = part[0];

  if (s_pos < k) {
    if (tid == 0) sh_LU = make_uint2(0u, 0u);               // ALLPOS mode
  } else if (s_above >= k) {
    if (tid == 0) sh_LU = make_uint2(FINE_HI, 0x7F7FFFFFu); // v64a >= 4
  } else if (s_above + tot_fine < k) {
    if (tid == 0) sh_LU = make_uint2(0u, FINE_LO);          // v64a < 2^-6
  } else {
    int nxt = (tid == 255) ? 0 : part[tid + 1];
    if (s_above + part[tid] >= k && (tid == 255 || s_above + nxt < k)) {
      int acc = s_above + nxt;                              // exactly one thread
      int bin = 0;
      for (int i = 7; i >= 0; --i) {
        acc += fine[tid * 8 + i];
        if (acc >= k) { bin = tid * 8 + i; break; }
      }
      unsigned L = (unsigned)(bin + (int)(FINE_LO >> 15)) << 15;
      sh_LU = make_uint2(L, L + (1u << 15));
    }
  }
  __syncthreads();

  // thresholds from bin edges
  unsigned ulo, uhi;
  {
    const uint2 t2 = sh_LU;
    if (t2.y == 0u) {              // ALLPOS: every positive is "hi", no band
      ulo = 0u; uhi = 0u;
    } else {
      float Lf = __uint_as_float(t2.x) - MARGIN;
      ulo = (Lf > 0.f) ? __float_as_uint(Lf) : 0u;
      float Uf = __uint_as_float(t2.y) + MARGIN;
      uhi = __float_as_uint(Uf);
    }
  }

  // ---- pass 2a: classify from global (L3-hot re-read of the 32KB row) ----
  {
    const u16x8* srcb = (const u16x8*)zrowb;
#pragma unroll
    for (int it = 0; it < 8; ++it) {
      int idx = tid + it * 256;
      u16x8 v = srcb[idx];
#pragma unroll
      for (int e = 0; e < 8; ++e) {
        unsigned short us = (unsigned short)v[e];
        if (us > 0 && us < 0x8000) {
          unsigned b = ((unsigned)us) << 16;
          if (b > uhi) {
            int pp = atomicAdd(&s_nh, 1);
            if (pp < HICAP) { hi_idx[pp] = idx * 8 + e; hi_val[pp] = __uint_as_float(b); }
          } else if (b > ulo) {
            int pp = atomicAdd(&s_nb, 1);
            if (pp < BDCAP) bd_idx[pp] = idx * 8 + e;
          }
        }
      }
    }
  }
  // ---- pass 2b: zero-write fp32 cols 0..8191 only (chunks 0..2047; same-
  //      thread ownership as the reads). Cols 8192+ zeroed by encode.
  {
    const float4 z4 = make_float4(0.f, 0.f, 0.f, 0.f);
    float4* p4 = (float4*)zrow;
#pragma unroll
    for (int jj = 0; jj < 8; ++jj) p4[tid + jj * 256] = z4;
  }
  __syncthreads();
  const int nh = (s_nh < HICAP) ? s_nh : HICAP;
  const int nb = (s_nb < BDCAP) ? s_nb : BDCAP;

  // exact fp32 recompute for band only -- IDENTICAL arithmetic to R2/R4-R13:
  // serial k=0..767 fmaf chain, then +bias; relu at ranking.
  for (int c = tid; c < nb; c += 256) {
    const float* wcol = WTf + (size_t)bd_idx[c] * DM;
    float s = 0.f;
#pragma unroll 8
    for (int i = 0; i < DM; ++i) s = fmaf(xs[i], wcol[i], s);
    cex[c] = s + be[bd_idx[c]];
  }
  __syncthreads();

  // --- build deterministic slot-ordered selection ---
  int nh_kept, need;
  if (nh <= k) {
    nh_kept = nh;
    need = k - nh;
    // hi slots ordered by index ascending
    for (int t = tid; t < nh; t += 256) {
      int myi = hi_idx[t];
      int r = 0;
      for (int c = 0; c < nh; ++c) r += (hi_idx[c] < myi);
      sidx[r] = myi; sval[r] = hi_val[t];
    }
  } else {
    // pathological: rank hi by (val desc, idx asc), keep top-k
    nh_kept = k;
    need = 0;
    for (int t = tid; t < nh; t += 256) {
      float er = hi_val[t];
      int myi = hi_idx[t];
      int r = 0;
      for (int c = 0; c < nh; ++c)
        r += (hi_val[c] > er) || (hi_val[c] == er && hi_idx[c] < myi);
      if (r < k) { sidx[r] = myi; sval[r] = er; }
    }
  }
  __syncthreads();

  // band: rank by (exact-relu desc, idx asc); take first `need`
  for (int t = tid; t < nb; t += 256) {
    float er = fmaxf(cex[t], 0.f);
    int myi = bd_idx[t];
    int r = 0;
    for (int c = 0; c < nb; ++c) {
      float ec = fmaxf(cex[c], 0.f);
      r += (ec > er) || (ec == er && bd_idx[c] < myi);
    }
    if (r < need) { sidx[nh_kept + r] = myi; sval[nh_kept + r] = er; }
  }
  __syncthreads();

  const int nsel = nh_kept + (need < nb ? need : nb);

  // scatter into the zeroed row (cols >= 8192 were zeroed by encode)
  if (tid < nsel) zrow[sidx[tid]] = sval[tid];

  // sparse decode: recon = sum_r sval[r] * W_dec[sidx[r],:] + b_dec
  float a0 = bd[tid], a1 = bd[tid + 256], a2 = bd[tid + 512];
  if (WdB) {
    for (int r = 0; r < nsel; ++r) {
      float v = sval[r];
      const unsigned short* wr = WdB + (size_t)sidx[r] * DM;
      a0 = fmaf(v, bf2f(wr[tid]),       a0);
      a1 = fmaf(v, bf2f(wr[tid + 256]), a1);
      a2 = fmaf(v, bf2f(wr[tid + 512]), a2);
    }
  } else {
    for (int r = 0; r < nsel; ++r) {
      float v = sval[r];
      const float* wr = Wd + (size_t)sidx[r] * DM;
      a0 = fmaf(v, wr[tid],       a0);
      a1 = fmaf(v, wr[tid + 256], a1);
      a2 = fmaf(v, wr[tid + 512], a2);
    }
  }
  float* rr = recon + (size_t)row * DM;
  rr[tid] = a0; rr[tid + 256] = a1; rr[tid + 512] = a2;
}

// ======================= FALLBACK PATH (R2, proven) =======================
#define BM 128
#define BN 128
#define BK 32

__global__ __launch_bounds__(256) void sae_encode_gemm(
    const float* __restrict__ x, const float* __restrict__ We,
    const float* __restrict__ be, float* __restrict__ pre)
{
  __shared__ float As2[BK][BM];
  __shared__ float Bs2[BK][BN];

  const int tid = threadIdx.x;
  const int bx  = blockIdx.x;
  const int by  = blockIdx.y;
  const int c0  = (tid & 15) * 4;
  const int r0  = (tid >> 4) * 4;

  float acc[2][2][4][4];
#pragma unroll
  for (int p = 0; p < 2; ++p)
#pragma unroll
    for (int qq = 0; qq < 2; ++qq)
#pragma unroll
      for (int i = 0; i < 4; ++i)
#pragma unroll
        for (int j = 0; j < 4; ++j) acc[p][qq][i][j] = 0.f;

  const float* xblk = x  + (size_t)by * BM * DM;
  const float* wblk = We + (size_t)bx * BN;

  for (int k0 = 0; k0 < DM; k0 += BK) {
#pragma unroll
    for (int i = 0; i < 4; ++i) {
      int s  = tid + i * 256;
      int m  = s >> 3;
      int kk4 = (s & 7) << 2;
      float4 v = *(const float4*)(xblk + (size_t)m * DM + (k0 + kk4));
      int cs = m ^ kk4;
      As2[kk4 + 0][cs] = v.x;
      As2[kk4 + 1][cs] = v.y;
      As2[kk4 + 2][cs] = v.z;
      As2[kk4 + 3][cs] = v.w;
    }
#pragma unroll
    for (int i = 0; i < 4; ++i) {
      int s  = tid + i * 256;
      int kk = s >> 5;
      int n  = (s & 31) << 2;
      *(float4*)&Bs2[kk][n] = *(const float4*)(wblk + (size_t)(k0 + kk) * DS + n);
    }
    __syncthreads();
#pragma unroll 4
    for (int kk = 0; kk < BK; ++kk) {
      const int kkm = kk & 0x1C;
      const int ra  = r0 ^ kkm;
      float4 a0 = *(const float4*)&As2[kk][ra];
      float4 a1 = *(const float4*)&As2[kk][ra + 64];
      float4 b0 = *(const float4*)&Bs2[kk][c0];
      float4 b1 = *(const float4*)&Bs2[kk][c0 + 64];
      float av[2][4] = {{a0.x, a0.y, a0.z, a0.w}, {a1.x, a1.y, a1.z, a1.w}};
      float bv[2][4] = {{b0.x, b0.y, b0.z, b0.w}, {b1.x, b1.y, b1.z, b1.w}};
#pragma unroll
      for (int p = 0; p < 2; ++p)
#pragma unroll
        for (int qq = 0; qq < 2; ++qq)
#pragma unroll
          for (int i = 0; i < 4; ++i)
#pragma unroll
            for (int j = 0; j < 4; ++j)
              acc[p][qq][i][j] = fmaf(av[p][i], bv[qq][j], acc[p][qq][i][j]);
    }
    __syncthreads();
  }

  const int row0 = by * BM + r0;
  const int col0 = bx * BN + c0;
  float bias[2][4];
#pragma unroll
  for (int qq = 0; qq < 2; ++qq)
#pragma unroll
    for (int j = 0; j < 4; ++j) bias[qq][j] = be[col0 + qq * 64 + j];
#pragma unroll
  for (int p = 0; p < 2; ++p)
#pragma unroll
    for (int i = 0; i < 4; ++i) {
      float* dst = pre + (size_t)(row0 + p * 64 + i) * DS + col0;
#pragma unroll
      for (int qq = 0; qq < 2; ++qq) {
        float4 o;
        o.x = fmaxf(acc[p][qq][i][0] + bias[qq][0], 0.f);
        o.y = fmaxf(acc[p][qq][i][1] + bias[qq][1], 0.f);
        o.z = fmaxf(acc[p][qq][i][2] + bias[qq][2], 0.f);
        o.w = fmaxf(acc[p][qq][i][3] + bias[qq][3], 0.f);
        *(float4*)(dst + qq * 64) = o;
      }
    }
}

__global__ __launch_bounds__(256) void sae_topk_decode(
    float* __restrict__ z, float* __restrict__ recon,
    const float* __restrict__ Wd, const float* __restrict__ bd,
    const int* __restrict__ kptr)
{
  const int row = blockIdx.x;
  const int tid = threadIdx.x;
  int k = *kptr;
  if (k < 1) k = 1;
  if (k > 1024) k = 1024;

  float* zrow = z + (size_t)row * DS;

  unsigned u[64];
  {
    const float4* src = (const float4*)zrow;
#pragma unroll
    for (int jj = 0; jj < 16; ++jj) {
      float4 v = src[tid + jj * 256];
      u[jj * 4 + 0] = (v.x > 0.f) ? __float_as_uint(v.x) : 0u;
      u[jj * 4 + 1] = (v.y > 0.f) ? __float_as_uint(v.y) : 0u;
      u[jj * 4 + 2] = (v.z > 0.f) ? __float_as_uint(v.z) : 0u;
      u[jj * 4 + 3] = (v.w > 0.f) ? __float_as_uint(v.w) : 0u;
    }
  }

  __shared__ int red[8];
  unsigned tbits = 0;
  for (int bit = 30; bit >= 0; --bit) {
    unsigned cand = tbits | (1u << bit);
    int c = 0;
#pragma unroll
    for (int j = 0; j < 64; ++j) c += (u[j] >= cand);
#pragma unroll
    for (int off = 32; off > 0; off >>= 1) c += __shfl_down(c, off, 64);
    if ((tid & 63) == 0) red[tid >> 6] = c;
    __syncthreads();
    int tot = red[0] + red[1] + red[2] + red[3];
    __syncthreads();
    if (tot >= k) tbits = cand;
  }

  int cnt_gt = 0, cnt_eq = 0;
  if (tbits != 0) {
    int c1 = 0, c2 = 0;
#pragma unroll
    for (int j = 0; j < 64; ++j) { c1 += (u[j] > tbits); c2 += (u[j] == tbits); }
#pragma unroll
    for (int off = 32; off > 0; off >>= 1) {
      c1 += __shfl_down(c1, off, 64);
      c2 += __shfl_down(c2, off, 64);
    }
    if ((tid & 63) == 0) { red[tid >> 6] = c1; red[4 + (tid >> 6)] = c2; }
    __syncthreads();
    cnt_gt = red[0] + red[1] + red[2] + red[3];
    cnt_eq = red[4] + red[5] + red[6] + red[7];
    __syncthreads();
  }
  const int needed = k - cnt_gt;

  __shared__ int eq_n;
  __shared__ int eq_keep;
  __shared__ int eq_idx[256];
  const bool rare = (tbits != 0) && (cnt_eq > needed);
  if (rare) {
    if (tid == 0) eq_n = 0;
    __syncthreads();
#pragma unroll
    for (int jj = 0; jj < 16; ++jj)
#pragma unroll
      for (int c = 0; c < 4; ++c) {
        int j = jj * 4 + c;
        if (u[j] == tbits) {
          int p = atomicAdd(&eq_n, 1);
          if (p < 256) eq_idx[p] = (tid + jj * 256) * 4 + c;
        }
      }
    __syncthreads();
    if (tid == 0) {
      int n = eq_n < 256 ? eq_n : 256;
      for (int a = 1; a < n; ++a) {
        int key = eq_idx[a]; int b = a - 1;
        while (b >= 0 && eq_idx[b] > key) { eq_idx[b + 1] = eq_idx[b]; --b; }
        eq_idx[b + 1] = key;
      }
      int kp = needed < n ? needed : n;
      eq_keep = kp < 0 ? 0 : kp;
    }
    __syncthreads();
  }

  unsigned long long mask = 0ull;
#pragma unroll
  for (int jj = 0; jj < 16; ++jj)
#pragma unroll
    for (int c = 0; c < 4; ++c) {
      int j = jj * 4 + c;
      bool s;
      if (tbits == 0) {
        s = (u[j] > 0u);
      } else if (u[j] > tbits) {
        s = true;
      } else if (u[j] == tbits) {
        if (!rare) s = true;
        else {
          int idx = (tid + jj * 256) * 4 + c;
          s = false;
          for (int e = 0; e < eq_keep; ++e)
            if (eq_idx[e] == idx) { s = true; break; }
        }
      } else s = false;
      if (s) mask |= (1ull << j);
    }
  const int mycount = __popcll(mask);

  __shared__ int scan[256];
  scan[tid] = mycount;
  __syncthreads();
  for (int off = 1; off < 256; off <<= 1) {
    int v = scan[tid];
    int add = (tid >= off) ? scan[tid - off] : 0;
    __syncthreads();
    scan[tid] = v + add;
    __syncthreads();
  }
  const int total = scan[255];
  int pos = scan[tid] - mycount;

  __shared__ float s_val[1024];
  __shared__ int   s_idx[1024];
  {
    float4* dst = (float4*)zrow;
#pragma unroll
    for (int jj = 0; jj < 16; ++jj) {
      float4 wv;
      float* wp = (float*)&wv;
#pragma unroll
      for (int c = 0; c < 4; ++c) {
        int j = jj * 4 + c;
        bool s = (mask >> j) & 1ull;
        float val = __uint_as_float(u[j]);
        wp[c] = s ? val : 0.f;
        if (s && pos < 1024) {
          s_idx[pos] = (tid + jj * 256) * 4 + c;
          s_val[pos] = val;
          ++pos;
        }
      }
      dst[tid + jj * 256] = wv;
    }
  }
  __syncthreads();

  float a0 = bd[tid], a1 = bd[tid + 256], a2 = bd[tid + 512];
  const int n = total < 1024 ? total : 1024;
#pragma unroll 4
  for (int i = 0; i < n; ++i) {
    float v = s_val[i];
    const float* wr = Wd + (size_t)s_idx[i] * DM;
    a0 = fmaf(v, wr[tid],       a0);
    a1 = fmaf(v, wr[tid + 256], a1);
    a2 = fmaf(v, wr[tid + 512], a2);
  }
  float* rr = recon + (size_t)row * DM;
  rr[tid] = a0; rr[tid + 256] = a1; rr[tid + 512] = a2;
}

// ------------------------------------------------------------------------------
extern "C" void kernel_launch(void* const* d_in, const int* in_sizes, int n_in,
                              void* d_out, int out_size, void* d_ws, size_t ws_size,
                              hipStream_t stream) {
  (void)in_sizes; (void)n_in; (void)out_size;

  const float* x     = (const float*)d_in[0];
  const float* W_enc = (const float*)d_in[1];
  const float* b_enc = (const float*)d_in[2];
  const float* W_dec = (const float*)d_in[3];
  const float* b_dec = (const float*)d_in[4];
  const int*   kp    = (const int*)d_in[5];

  float* z     = (float*)d_out;                    // [NROWS][DS]
  float* recon = z + (size_t)NROWS * DS;           // [NROWS][DM]

  const size_t sz_WTf = (size_t)DS * DM * 4;       // 50,331,648
  const size_t sz_WTb = (size_t)DS * DM * 2;       // 25,165,824
  const size_t sz_xb  = (size_t)NROWS * DM * 2;    // 12,582,912
  const size_t sz_WdB = (size_t)DS * DM * 2;       // 25,165,824
  const size_t need_small = sz_WTf + sz_WTb + sz_xb;            //  88 MB
  const size_t need_big   = need_small + sz_WdB;                // 113 MB

  if (ws_size >= need_small) {
    float*          WTf = (float*)d_ws;
    unsigned short* WTb = (unsigned short*)((char*)d_ws + sz_WTf);
    unsigned short* xb  = (unsigned short*)((char*)d_ws + sz_WTf + sz_WTb);
    unsigned short* WdB = nullptr;

    cvt_x_bf16<<<(NROWS * DM) / (4 * 256), 256, 0, stream>>>(x, xb);
    if (ws_size >= need_big) {
      WdB = (unsigned short*)((char*)d_ws + need_small);
      cvt_wd_bf16<<<((size_t)DS * DM) / (4 * 256), 256, 0, stream>>>(W_dec, WdB);
    }
    transpose_w<<<dim3(DS / 32, DM / 32), 256, 0, stream>>>(W_enc, WTf, WTb);
    sae_encode_bf16<<<dim3(DS / 128, NROWS / 128), 256, 0, stream>>>(
        xb, WTb, b_enc, (unsigned short*)z, z);
    sae_topk_fused<<<NROWS, 256, 0, stream>>>(z, recon, x, WTf, b_enc,
                                              W_dec, WdB, b_dec, kp);
  } else {
    sae_encode_gemm<<<dim3(DS / BN, NROWS / BM), 256, 0, stream>>>(x, W_enc, b_enc, z);
    sae_topk_decode<<<NROWS, 256, 0, stream>>>(z, recon, W_dec, b_dec, kp);
  }
}

// Round 15
// 840.900 us; speedup vs baseline: 1.0340x; 1.0030x over previous
//
#include <hip/hip_runtime.h>
#include <cstdint>

// Problem constants (fixed by the harness inputs)
#define NROWS 8192
#define DM    768
#define DS    16384
#define PREB_STRIDE 32768   // ushort elements: bf16 row r lives in the first
                            // half of fp32 z-row r's own 64KB span (race-free)

typedef __attribute__((ext_vector_type(8))) short          bf16x8;
typedef __attribute__((ext_vector_type(8))) unsigned short u16x8;
typedef __attribute__((ext_vector_type(4))) float          f32x4;

__device__ __forceinline__ unsigned short f2bf(float f) {
  unsigned u = __float_as_uint(f);
  unsigned r = u + 0x7fffu + ((u >> 16) & 1u);   // RNE
  return (unsigned short)(r >> 16);
}
__device__ __forceinline__ float bf2f(unsigned short us) {
  return __uint_as_float(((unsigned)us) << 16);
}

// async 16B global->LDS DMA; lds dest must be wave-uniform (HW writes
// base + lane*16), global src is per-lane (m97/m104/m173 semantics).
#define GLOAD_LDS16(g, l)                                                     \
  __builtin_amdgcn_global_load_lds(                                           \
      (const __attribute__((address_space(1))) void*)(g),                     \
      (__attribute__((address_space(3))) void*)(l), 16, 0, 0)

#define MARGIN 0.04f
// fine range: value in [2^-6, 4.0) <=> bits in [0x3C800000, 0x40800000)
#define FINE_LO 0x3C800000u
#define FINE_HI 0x40800000u
#define HICAP 256
#define BDCAP 512
#define SELCAP 160

// ======================= FAST PATH (needs ~88/113MB workspace) =================

// ---- prep 1: x fp32 -> bf16 ----
__global__ __launch_bounds__(256) void cvt_x_bf16(const float* __restrict__ x,
                                                  unsigned short* __restrict__ xb) {
  int i = blockIdx.x * 256 + threadIdx.x;        // float4 index; grid covers exactly
  float4 v = ((const float4*)x)[i];
  ushort4 o;
  o.x = f2bf(v.x); o.y = f2bf(v.y); o.z = f2bf(v.z); o.w = f2bf(v.w);
  ((ushort4*)xb)[i] = o;
}

// ---- prep 1b: W_dec fp32 -> bf16 (decode table; halves gather traffic) ----
__global__ __launch_bounds__(256) void cvt_wd_bf16(const float* __restrict__ wd,
                                                   unsigned short* __restrict__ wdb) {
  int i = blockIdx.x * 256 + threadIdx.x;        // float4 index; grid covers exactly
  float4 v = ((const float4*)wd)[i];
  ushort4 o;
  o.x = f2bf(v.x); o.y = f2bf(v.y); o.z = f2bf(v.z); o.w = f2bf(v.w);
  ((ushort4*)wdb)[i] = o;
}

// ---- prep 2: W_enc [DM][DS] -> WTf fp32 [DS][DM] + WTb bf16 [DS][DM] ----
__global__ __launch_bounds__(256) void transpose_w(const float* __restrict__ We,
                                                   float* __restrict__ WTf,
                                                   unsigned short* __restrict__ WTb) {
  __shared__ float t[32][33];
  const int c0 = blockIdx.x * 32;   // DS dim
  const int r0 = blockIdx.y * 32;   // DM dim
  const int tx = threadIdx.x & 31, ty = threadIdx.x >> 5;  // ty 0..7
#pragma unroll
  for (int i = 0; i < 4; ++i)
    t[ty + i * 8][tx] = We[(size_t)(r0 + ty + i * 8) * DS + c0 + tx];
  __syncthreads();
#pragma unroll
  for (int i = 0; i < 4; ++i) {
    float v = t[tx][ty + i * 8];
    size_t o = (size_t)(c0 + ty + i * 8) * DM + r0 + tx;
    WTf[o] = v;
    WTb[o] = f2bf(v);
  }
}

// ---- approx encode (R14, proven): preb = bf16(x@We + be) via MFMA;
//      2-phase double-buffered global_load_lds staging; blocks with
//      n0 >= DS/2 zero the upper-half fp32 z tile (disjoint bytes).
__global__ __launch_bounds__(256) void sae_encode_bf16(
    const unsigned short* __restrict__ xb,   // [NROWS][DM] bf16
    const unsigned short* __restrict__ WTb,  // [DS][DM] bf16 (W_enc^T)
    const float* __restrict__ be,            // [DS]
    unsigned short* __restrict__ preb,       // [NROWS][PREB_STRIDE] bf16 approx
    float* __restrict__ zfull)               // fp32 z view of the same region
{
  __shared__ __align__(16) short As[2][128 * 64];
  __shared__ __align__(16) short Bs[2][128 * 64];

  const int tid  = threadIdx.x;
  const int lane = tid & 63;
  const int w    = tid >> 6;          // wave 0..3
  const int wm   = w >> 1, wn = w & 1;
  const int m0   = blockIdx.y * 128, n0 = blockIdx.x * 128;
  const int l15  = lane & 15, q = lane >> 4, l7 = lane & 7;

  f32x4 acc[4][4];
  const f32x4 zero4 = {0.f, 0.f, 0.f, 0.f};
#pragma unroll
  for (int i = 0; i < 4; ++i)
#pragma unroll
    for (int j = 0; j < 4; ++j) acc[i][j] = zero4;

  auto stage = [&](int buf, int k0) {
#pragma unroll
    for (int j = 0; j < 4; ++j) {
      int pj  = (w << 8) + (j << 6) + lane;
      int m   = pj >> 3, gp = pj & 7;
      int col = ((gp ^ (m & 7)) << 3);          // ushort offset within row
      const unsigned short* ga = xb  + (size_t)(m0 + m) * DM + k0 + col;
      const unsigned short* gb = WTb + (size_t)(n0 + m) * DM + k0 + col;
      int ldsoff = ((w << 8) + (j << 6)) << 4;  // wave-uniform byte base
      GLOAD_LDS16(ga, (char*)As[buf] + ldsoff);
      GLOAD_LDS16(gb, (char*)Bs[buf] + ldsoff);
    }
  };

  stage(0, 0);
  __syncthreads();                      // buf0 ready (barrier drains vmcnt)

  int cur = 0;
  const int NT = DM / 64;               // 12 K-steps
  for (int t = 0; t < NT; ++t) {
    if (t + 1 < NT) stage(cur ^ 1, (t + 1) * 64);   // prefetch next tile

    const char* Ab = (const char*)As[cur];
    const char* Bb = (const char*)Bs[cur];
#pragma unroll
    for (int h = 0; h < 2; ++h) {
      const int gsw = (((h * 4 + q) ^ l7) << 4);
      bf16x8 af[4], bfr[4];
#pragma unroll
      for (int tt = 0; tt < 4; ++tt) {
        af[tt]  = *(const bf16x8*)(Ab + (wm * 64 + tt * 16 + l15) * 128 + gsw);
        bfr[tt] = *(const bf16x8*)(Bb + (wn * 64 + tt * 16 + l15) * 128 + gsw);
      }
#pragma unroll
      for (int mf = 0; mf < 4; ++mf)
#pragma unroll
        for (int nf = 0; nf < 4; ++nf)
          acc[mf][nf] = __builtin_amdgcn_mfma_f32_16x16x32_bf16(
              af[mf], bfr[nf], acc[mf][nf], 0, 0, 0);
    }
    __syncthreads();   // drains prefetch (vmcnt0) + guards buf reuse
    cur ^= 1;
  }

#pragma unroll
  for (int nf = 0; nf < 4; ++nf) {
    const int gcol = n0 + wn * 64 + nf * 16 + l15;
    const float bias = be[gcol];
#pragma unroll
    for (int mf = 0; mf < 4; ++mf) {
#pragma unroll
      for (int r = 0; r < 4; ++r) {
        int grow = m0 + wm * 64 + mf * 16 + q * 4 + r;
        preb[(size_t)grow * PREB_STRIDE + gcol] = f2bf(acc[mf][nf][r] + bias);
      }
    }
  }

  if (n0 >= DS / 2) {
    const float4 z4 = make_float4(0.f, 0.f, 0.f, 0.f);
    const int r0w = tid >> 5;            // 0..7
    const int c0w = (tid & 31) << 2;     // 0..124
#pragma unroll
    for (int i = 0; i < 16; ++i) {
      *(float4*)(zfull + (size_t)(m0 + r0w + i * 8) * DS + n0 + c0w) = z4;
    }
  }
}

// ---- FUSED select+exact. R15 change: decode gather loop hand-unrolled 4x
//      with HOISTED loads (12 independent loads, then fmafs in the ORIGINAL
//      r-ascending order -> bit-identical result). launch_bounds(256,4)
//      lifts the 20-VGPR starvation that serialized the gathers (R14 PMC).
__global__ __launch_bounds__(256, 4) void sae_topk_fused(
    float* __restrict__ z,            // z region; bf16 row r in first half of span r
    float* __restrict__ recon,        // [NROWS][DM]
    const float* __restrict__ x,      // fp32 [NROWS][DM]
    const float* __restrict__ WTf,    // fp32 [DS][DM] (W_enc^T)
    const float* __restrict__ be,     // [DS]
    const float* __restrict__ Wd,     // [DS][DM] fp32
    const unsigned short* __restrict__ WdB,  // [DS][DM] bf16 copy (or nullptr)
    const float* __restrict__ bd,     // [DM]
    const int* __restrict__ kptr)
{
  const int row = blockIdx.x;
  const int tid = threadIdx.x;
  int k = *kptr; if (k < 1) k = 1; if (k > 128) k = 128;  // harness k = 64

  float* zrow = z + (size_t)row * DS;
  const unsigned short* zrowb = (const unsigned short*)zrow;  // bf16 alias, same span

  __shared__ int   fine[2048];
  __shared__ int   part[256];
  __shared__ int   s_above, s_pos;
  __shared__ uint2 sh_LU;
  __shared__ float xs[DM];
  __shared__ int   hi_idx[HICAP];
  __shared__ float hi_val[HICAP];
  __shared__ int   bd_idx[BDCAP];
  __shared__ float cex[BDCAP];
  __shared__ int   s_nh, s_nb;
  __shared__ int   sidx[SELCAP];
  __shared__ float sval[SELCAP];

#pragma unroll
  for (int i = 0; i < 8; ++i) fine[tid + i * 256] = 0;
  if (tid == 0) { s_above = 0; s_pos = 0; s_nh = 0; s_nb = 0; }
  for (int i = tid; i < DM; i += 256) xs[i] = x[(size_t)row * DM + i];
  __syncthreads();

  // ---- pass 1: read bf16 row + fine histogram ----
  int above_c = 0, pos_c = 0;
  {
    const u16x8* srcb = (const u16x8*)zrowb;
#pragma unroll
    for (int it = 0; it < 8; ++it) {
      int idx = tid + it * 256;                 // 16B chunk index (2048 total)
      u16x8 v = srcb[idx];
#pragma unroll
      for (int e = 0; e < 8; ++e) {
        unsigned short us = (unsigned short)v[e];
        if (us > 0 && us < 0x8000) {            // positive bf16
          ++pos_c;
          unsigned b = ((unsigned)us) << 16;
          if (b >= FINE_HI) ++above_c;
          else if (b >= FINE_LO) atomicAdd(&fine[(b >> 15) - (FINE_LO >> 15)], 1);
        }
      }
    }
  }
  if (above_c) atomicAdd(&s_above, above_c);
  if (pos_c)   atomicAdd(&s_pos, pos_c);
  __syncthreads();

  // suffix (from-top) inclusive scan over 256 groups of 8 bins
  int p = 0;
#pragma unroll
  for (int i = 0; i < 8; ++i) p += fine[tid * 8 + i];
  part[tid] = p;
  __syncthreads();
  for (int off = 1; off < 256; off <<= 1) {
    int v = part[tid];
    int add = (tid + off < 256) ? part[tid + off] : 0;
    __syncthreads();
    part[tid] = v + add;
    __syncthreads();
  }
  const int tot_fine = part[0];

  if (s_pos < k) {
    if (tid == 0) sh_LU = make_uint2(0u, 0u);               // ALLPOS mode
  } else if (s_above >= k) {
    if (tid == 0) sh_LU = make_uint2(FINE_HI, 0x7F7FFFFFu); // v64a >= 4
  } else if (s_above + tot_fine < k) {
    if (tid == 0) sh_LU = make_uint2(0u, FINE_LO);          // v64a < 2^-6
  } else {
    int nxt = (tid == 255) ? 0 : part[tid + 1];
    if (s_above + part[tid] >= k && (tid == 255 || s_above + nxt < k)) {
      int acc = s_above + nxt;                              // exactly one thread
      int bin = 0;
      for (int i = 7; i >= 0; --i) {
        acc += fine[tid * 8 + i];
        if (acc >= k) { bin = tid * 8 + i; break; }
      }
      unsigned L = (unsigned)(bin + (int)(FINE_LO >> 15)) << 15;
      sh_LU = make_uint2(L, L + (1u << 15));
    }
  }
  __syncthreads();

  // thresholds from bin edges
  unsigned ulo, uhi;
  {
    const uint2 t2 = sh_LU;
    if (t2.y == 0u) {              // ALLPOS: every positive is "hi", no band
      ulo = 0u; uhi = 0u;
    } else {
      float Lf = __uint_as_float(t2.x) - MARGIN;
      ulo = (Lf > 0.f) ? __float_as_uint(Lf) : 0u;
      float Uf = __uint_as_float(t2.y) + MARGIN;
      uhi = __float_as_uint(Uf);
    }
  }

  // ---- pass 2a: classify from global (L3-hot re-read of the 32KB row) ----
  {
    const u16x8* srcb = (const u16x8*)zrowb;
#pragma unroll
    for (int it = 0; it < 8; ++it) {
      int idx = tid + it * 256;
      u16x8 v = srcb[idx];
#pragma unroll
      for (int e = 0; e < 8; ++e) {
        unsigned short us = (unsigned short)v[e];
        if (us > 0 && us < 0x8000) {
          unsigned b = ((unsigned)us) << 16;
          if (b > uhi) {
            int pp = atomicAdd(&s_nh, 1);
            if (pp < HICAP) { hi_idx[pp] = idx * 8 + e; hi_val[pp] = __uint_as_float(b); }
          } else if (b > ulo) {
            int pp = atomicAdd(&s_nb, 1);
            if (pp < BDCAP) bd_idx[pp] = idx * 8 + e;
          }
        }
      }
    }
  }
  // ---- pass 2b: zero-write fp32 cols 0..8191 only (chunks 0..2047; same-
  //      thread ownership as the reads). Cols 8192+ zeroed by encode.
  {
    const float4 z4 = make_float4(0.f, 0.f, 0.f, 0.f);
    float4* p4 = (float4*)zrow;
#pragma unroll
    for (int jj = 0; jj < 8; ++jj) p4[tid + jj * 256] = z4;
  }
  __syncthreads();
  const int nh = (s_nh < HICAP) ? s_nh : HICAP;
  const int nb = (s_nb < BDCAP) ? s_nb : BDCAP;

  // exact fp32 recompute for band only -- IDENTICAL arithmetic to R2/R4-R14:
  // serial k=0..767 fmaf chain, then +bias; relu at ranking.
  for (int c = tid; c < nb; c += 256) {
    const float* wcol = WTf + (size_t)bd_idx[c] * DM;
    float s = 0.f;
#pragma unroll 8
    for (int i = 0; i < DM; ++i) s = fmaf(xs[i], wcol[i], s);
    cex[c] = s + be[bd_idx[c]];
  }
  __syncthreads();

  // --- build deterministic slot-ordered selection ---
  int nh_kept, need;
  if (nh <= k) {
    nh_kept = nh;
    need = k - nh;
    // hi slots ordered by index ascending
    for (int t = tid; t < nh; t += 256) {
      int myi = hi_idx[t];
      int r = 0;
      for (int c = 0; c < nh; ++c) r += (hi_idx[c] < myi);
      sidx[r] = myi; sval[r] = hi_val[t];
    }
  } else {
    // pathological: rank hi by (val desc, idx asc), keep top-k
    nh_kept = k;
    need = 0;
    for (int t = tid; t < nh; t += 256) {
      float er = hi_val[t];
      int myi = hi_idx[t];
      int r = 0;
      for (int c = 0; c < nh; ++c)
        r += (hi_val[c] > er) || (hi_val[c] == er && hi_idx[c] < myi);
      if (r < k) { sidx[r] = myi; sval[r] = er; }
    }
  }
  __syncthreads();

  // band: rank by (exact-relu desc, idx asc); take first `need`
  for (int t = tid; t < nb; t += 256) {
    float er = fmaxf(cex[t], 0.f);
    int myi = bd_idx[t];
    int r = 0;
    for (int c = 0; c < nb; ++c) {
      float ec = fmaxf(cex[c], 0.f);
      r += (ec > er) || (ec == er && bd_idx[c] < myi);
    }
    if (r < need) { sidx[nh_kept + r] = myi; sval[nh_kept + r] = er; }
  }
  __syncthreads();

  const int nsel = nh_kept + (need < nb ? need : nb);

  // scatter into the zeroed row (cols >= 8192 were zeroed by encode)
  if (tid < nsel) zrow[sidx[tid]] = sval[tid];

  // sparse decode: recon = sum_r sval[r] * W_dec[sidx[r],:] + b_dec
  // R15: 4x unroll with hoisted loads (ILP); fmaf ORDER UNCHANGED (r asc)
  float a0 = bd[tid], a1 = bd[tid + 256], a2 = bd[tid + 512];
  if (WdB) {
    int r = 0;
    for (; r + 4 <= nsel; r += 4) {
      const unsigned short* w0 = WdB + (size_t)sidx[r + 0] * DM;
      const unsigned short* w1 = WdB + (size_t)sidx[r + 1] * DM;
      const unsigned short* w2 = WdB + (size_t)sidx[r + 2] * DM;
      const unsigned short* w3 = WdB + (size_t)sidx[r + 3] * DM;
      float v0 = sval[r + 0], v1 = sval[r + 1];
      float v2 = sval[r + 2], v3 = sval[r + 3];
      unsigned short t00 = w0[tid], t01 = w0[tid + 256], t02 = w0[tid + 512];
      unsigned short t10 = w1[tid], t11 = w1[tid + 256], t12 = w1[tid + 512];
      unsigned short t20 = w2[tid], t21 = w2[tid + 256], t22 = w2[tid + 512];
      unsigned short t30 = w3[tid], t31 = w3[tid + 256], t32 = w3[tid + 512];
      a0 = fmaf(v0, bf2f(t00), a0); a1 = fmaf(v0, bf2f(t01), a1); a2 = fmaf(v0, bf2f(t02), a2);
      a0 = fmaf(v1, bf2f(t10), a0); a1 = fmaf(v1, bf2f(t11), a1); a2 = fmaf(v1, bf2f(t12), a2);
      a0 = fmaf(v2, bf2f(t20), a0); a1 = fmaf(v2, bf2f(t21), a1); a2 = fmaf(v2, bf2f(t22), a2);
      a0 = fmaf(v3, bf2f(t30), a0); a1 = fmaf(v3, bf2f(t31), a1); a2 = fmaf(v3, bf2f(t32), a2);
    }
    for (; r < nsel; ++r) {
      float v = sval[r];
      const unsigned short* wr = WdB + (size_t)sidx[r] * DM;
      a0 = fmaf(v, bf2f(wr[tid]),       a0);
      a1 = fmaf(v, bf2f(wr[tid + 256]), a1);
      a2 = fmaf(v, bf2f(wr[tid + 512]), a2);
    }
  } else {
    int r = 0;
    for (; r + 4 <= nsel; r += 4) {
      const float* w0 = Wd + (size_t)sidx[r + 0] * DM;
      const float* w1 = Wd + (size_t)sidx[r + 1] * DM;
      const float* w2 = Wd + (size_t)sidx[r + 2] * DM;
      const float* w3 = Wd + (size_t)sidx[r + 3] * DM;
      float v0 = sval[r + 0], v1 = sval[r + 1];
      float v2 = sval[r + 2], v3 = sval[r + 3];
      float t00 = w0[tid], t01 = w0[tid + 256], t02 = w0[tid + 512];
      float t10 = w1[tid], t11 = w1[tid + 256], t12 = w1[tid + 512];
      float t20 = w2[tid], t21 = w2[tid + 256], t22 = w2[tid + 512];
      float t30 = w3[tid], t31 = w3[tid + 256], t32 = w3[tid + 512];
      a0 = fmaf(v0, t00, a0); a1 = fmaf(v0, t01, a1); a2 = fmaf(v0, t02, a2);
      a0 = fmaf(v1, t10, a0); a1 = fmaf(v1, t11, a1); a2 = fmaf(v1, t12, a2);
      a0 = fmaf(v2, t20, a0); a1 = fmaf(v2, t21, a1); a2 = fmaf(v2, t22, a2);
      a0 = fmaf(v3, t30, a0); a1 = fmaf(v3, t31, a1); a2 = fmaf(v3, t32, a2);
    }
    for (; r < nsel; ++r) {
      float v = sval[r];
      const float* wr = Wd + (size_t)sidx[r] * DM;
      a0 = fmaf(v, wr[tid],       a0);
      a1 = fmaf(v, wr[tid + 256], a1);
      a2 = fmaf(v, wr[tid + 512], a2);
    }
  }
  float* rr = recon + (size_t)row * DM;
  rr[tid] = a0; rr[tid + 256] = a1; rr[tid + 512] = a2;
}

// ======================= FALLBACK PATH (R2, proven) =======================
#define BM 128
#define BN 128
#define BK 32

__global__ __launch_bounds__(256) void sae_encode_gemm(
    const float* __restrict__ x, const float* __restrict__ We,
    const float* __restrict__ be, float* __restrict__ pre)
{
  __shared__ float As2[BK][BM];
  __shared__ float Bs2[BK][BN];

  const int tid = threadIdx.x;
  const int bx  = blockIdx.x;
  const int by  = blockIdx.y;
  const int c0  = (tid & 15) * 4;
  const int r0  = (tid >> 4) * 4;

  float acc[2][2][4][4];
#pragma unroll
  for (int p = 0; p < 2; ++p)
#pragma unroll
    for (int qq = 0; qq < 2; ++qq)
#pragma unroll
      for (int i = 0; i < 4; ++i)
#pragma unroll
        for (int j = 0; j < 4; ++j) acc[p][qq][i][j] = 0.f;

  const float* xblk = x  + (size_t)by * BM * DM;
  const float* wblk = We + (size_t)bx * BN;

  for (int k0 = 0; k0 < DM; k0 += BK) {
#pragma unroll
    for (int i = 0; i < 4; ++i) {
      int s  = tid + i * 256;
      int m  = s >> 3;
      int kk4 = (s & 7) << 2;
      float4 v = *(const float4*)(xblk + (size_t)m * DM + (k0 + kk4));
      int cs = m ^ kk4;
      As2[kk4 + 0][cs] = v.x;
      As2[kk4 + 1][cs] = v.y;
      As2[kk4 + 2][cs] = v.z;
      As2[kk4 + 3][cs] = v.w;
    }
#pragma unroll
    for (int i = 0; i < 4; ++i) {
      int s  = tid + i * 256;
      int kk = s >> 5;
      int n  = (s & 31) << 2;
      *(float4*)&Bs2[kk][n] = *(const float4*)(wblk + (size_t)(k0 + kk) * DS + n);
    }
    __syncthreads();
#pragma unroll 4
    for (int kk = 0; kk < BK; ++kk) {
      const int kkm = kk & 0x1C;
      const int ra  = r0 ^ kkm;
      float4 a0 = *(const float4*)&As2[kk][ra];
      float4 a1 = *(const float4*)&As2[kk][ra + 64];
      float4 b0 = *(const float4*)&Bs2[kk][c0];
      float4 b1 = *(const float4*)&Bs2[kk][c0 + 64];
      float av[2][4] = {{a0.x, a0.y, a0.z, a0.w}, {a1.x, a1.y, a1.z, a1.w}};
      float bv[2][4] = {{b0.x, b0.y, b0.z, b0.w}, {b1.x, b1.y, b1.z, b1.w}};
#pragma unroll
      for (int p = 0; p < 2; ++p)
#pragma unroll
        for (int qq = 0; qq < 2; ++qq)
#pragma unroll
          for (int i = 0; i < 4; ++i)
#pragma unroll
            for (int j = 0; j < 4; ++j)
              acc[p][qq][i][j] = fmaf(av[p][i], bv[qq][j], acc[p][qq][i][j]);
    }
    __syncthreads();
  }

  const int row0 = by * BM + r0;
  const int col0 = bx * BN + c0;
  float bias[2][4];
#pragma unroll
  for (int qq = 0; qq < 2; ++qq)
#pragma unroll
    for (int j = 0; j < 4; ++j) bias[qq][j] = be[col0 + qq * 64 + j];
#pragma unroll
  for (int p = 0; p < 2; ++p)
#pragma unroll
    for (int i = 0; i < 4; ++i) {
      float* dst = pre + (size_t)(row0 + p * 64 + i) * DS + col0;
#pragma unroll
      for (int qq = 0; qq < 2; ++qq) {
        float4 o;
        o.x = fmaxf(acc[p][qq][i][0] + bias[qq][0], 0.f);
        o.y = fmaxf(acc[p][qq][i][1] + bias[qq][1], 0.f);
        o.z = fmaxf(acc[p][qq][i][2] + bias[qq][2], 0.f);
        o.w = fmaxf(acc[p][qq][i][3] + bias[qq][3], 0.f);
        *(float4*)(dst + qq * 64) = o;
      }
    }
}

__global__ __launch_bounds__(256) void sae_topk_decode(
    float* __restrict__ z, float* __restrict__ recon,
    const float* __restrict__ Wd, const float* __restrict__ bd,
    const int* __restrict__ kptr)
{
  const int row = blockIdx.x;
  const int tid = threadIdx.x;
  int k = *kptr;
  if (k < 1) k = 1;
  if (k > 1024) k = 1024;

  float* zrow = z + (size_t)row * DS;

  unsigned u[64];
  {
    const float4* src = (const float4*)zrow;
#pragma unroll
    for (int jj = 0; jj < 16; ++jj) {
      float4 v = src[tid + jj * 256];
      u[jj * 4 + 0] = (v.x > 0.f) ? __float_as_uint(v.x) : 0u;
      u[jj * 4 + 1] = (v.y > 0.f) ? __float_as_uint(v.y) : 0u;
      u[jj * 4 + 2] = (v.z > 0.f) ? __float_as_uint(v.z) : 0u;
      u[jj * 4 + 3] = (v.w > 0.f) ? __float_as_uint(v.w) : 0u;
    }
  }

  __shared__ int red[8];
  unsigned tbits = 0;
  for (int bit = 30; bit >= 0; --bit) {
    unsigned cand = tbits | (1u << bit);
    int c = 0;
#pragma unroll
    for (int j = 0; j < 64; ++j) c += (u[j] >= cand);
#pragma unroll
    for (int off = 32; off > 0; off >>= 1) c += __shfl_down(c, off, 64);
    if ((tid & 63) == 0) red[tid >> 6] = c;
    __syncthreads();
    int tot = red[0] + red[1] + red[2] + red[3];
    __syncthreads();
    if (tot >= k) tbits = cand;
  }

  int cnt_gt = 0, cnt_eq = 0;
  if (tbits != 0) {
    int c1 = 0, c2 = 0;
#pragma unroll
    for (int j = 0; j < 64; ++j) { c1 += (u[j] > tbits); c2 += (u[j] == tbits); }
#pragma unroll
    for (int off = 32; off > 0; off >>= 1) {
      c1 += __shfl_down(c1, off, 64);
      c2 += __shfl_down(c2, off, 64);
    }
    if ((tid & 63) == 0) { red[tid >> 6] = c1; red[4 + (tid >> 6)] = c2; }
    __syncthreads();
    cnt_gt = red[0] + red[1] + red[2] + red[3];
    cnt_eq = red[4] + red[5] + red[6] + red[7];
    __syncthreads();
  }
  const int needed = k - cnt_gt;

  __shared__ int eq_n;
  __shared__ int eq_keep;
  __shared__ int eq_idx[256];
  const bool rare = (tbits != 0) && (cnt_eq > needed);
  if (rare) {
    if (tid == 0) eq_n = 0;
    __syncthreads();
#pragma unroll
    for (int jj = 0; jj < 16; ++jj)
#pragma unroll
      for (int c = 0; c < 4; ++c) {
        int j = jj * 4 + c;
        if (u[j] == tbits) {
          int p = atomicAdd(&eq_n, 1);
          if (p < 256) eq_idx[p] = (tid + jj * 256) * 4 + c;
        }
      }
    __syncthreads();
    if (tid == 0) {
      int n = eq_n < 256 ? eq_n : 256;
      for (int a = 1; a < n; ++a) {
        int key = eq_idx[a]; int b = a - 1;
        while (b >= 0 && eq_idx[b] > key) { eq_idx[b + 1] = eq_idx[b]; --b; }
        eq_idx[b + 1] = key;
      }
      int kp = needed < n ? needed : n;
      eq_keep = kp < 0 ? 0 : kp;
    }
    __syncthreads();
  }

  unsigned long long mask = 0ull;
#pragma unroll
  for (int jj = 0; jj < 16; ++jj)
#pragma unroll
    for (int c = 0; c < 4; ++c) {
      int j = jj * 4 + c;
      bool s;
      if (tbits == 0) {
        s = (u[j] > 0u);
      } else if (u[j] > tbits) {
        s = true;
      } else if (u[j] == tbits) {
        if (!rare) s = true;
        else {
          int idx = (tid + jj * 256) * 4 + c;
          s = false;
          for (int e = 0; e < eq_keep; ++e)
            if (eq_idx[e] == idx) { s = true; break; }
        }
      } else s = false;
      if (s) mask |= (1ull << j);
    }
  const int mycount = __popcll(mask);

  __shared__ int scan[256];
  scan[tid] = mycount;
  __syncthreads();
  for (int off = 1; off < 256; off <<= 1) {
    int v = scan[tid];
    int add = (tid >= off) ? scan[tid - off] : 0;
    __syncthreads();
    scan[tid] = v + add;
    __syncthreads();
  }
  const int total = scan[255];
  int pos = scan[tid] - mycount;

  __shared__ float s_val[1024];
  __shared__ int   s_idx[1024];
  {
    float4* dst = (float4*)zrow;
#pragma unroll
    for (int jj = 0; jj < 16; ++jj) {
      float4 wv;
      float* wp = (float*)&wv;
#pragma unroll
      for (int c = 0; c < 4; ++c) {
        int j = jj * 4 + c;
        bool s = (mask >> j) & 1ull;
        float val = __uint_as_float(u[j]);
        wp[c] = s ? val : 0.f;
        if (s && pos < 1024) {
          s_idx[pos] = (tid + jj * 256) * 4 + c;
          s_val[pos] = val;
          ++pos;
        }
      }
      dst[tid + jj * 256] = wv;
    }
  }
  __syncthreads();

  float a0 = bd[tid], a1 = bd[tid + 256], a2 = bd[tid + 512];
  const int n = total < 1024 ? total : 1024;
#pragma unroll 4
  for (int i = 0; i < n; ++i) {
    float v = s_val[i];
    const float* wr = Wd + (size_t)s_idx[i] * DM;
    a0 = fmaf(v, wr[tid],       a0);
    a1 = fmaf(v, wr[tid + 256], a1);
    a2 = fmaf(v, wr[tid + 512], a2);
  }
  float* rr = recon + (size_t)row * DM;
  rr[tid] = a0; rr[tid + 256] = a1; rr[tid + 512] = a2;
}

// ------------------------------------------------------------------------------
extern "C" void kernel_launch(void* const* d_in, const int* in_sizes, int n_in,
                              void* d_out, int out_size, void* d_ws, size_t ws_size,
                              hipStream_t stream) {
  (void)in_sizes; (void)n_in; (void)out_size;

  const float* x     = (const float*)d_in[0];
  const float* W_enc = (const float*)d_in[1];
  const float* b_enc = (const float*)d_in[2];
  const float* W_dec = (const float*)d_in[3];
  const float* b_dec = (const float*)d_in[4];
  const int*   kp    = (const int*)d_in[5];

  float* z     = (float*)d_out;                    // [NROWS][DS]
  float* recon = z + (size_t)NROWS * DS;           // [NROWS][DM]

  const size_t sz_WTf = (size_t)DS * DM * 4;       // 50,331,648
  const size_t sz_WTb = (size_t)DS * DM * 2;       // 25,165,824
  const size_t sz_xb  = (size_t)NROWS * DM * 2;    // 12,582,912
  const size_t sz_WdB = (size_t)DS * DM * 2;       // 25,165,824
  const size_t need_small = sz_WTf + sz_WTb + sz_xb;            //  88 MB
  const size_t need_big   = need_small + sz_WdB;                // 113 MB

  if (ws_size >= need_small) {
    float*          WTf = (float*)d_ws;
    unsigned short* WTb = (unsigned short*)((char*)d_ws + sz_WTf);
    unsigned short* xb  = (unsigned short*)((char*)d_ws + sz_WTf + sz_WTb);
    unsigned short* WdB = nullptr;

    cvt_x_bf16<<<(NROWS * DM) / (4 * 256), 256, 0, stream>>>(x, xb);
    if (ws_size >= need_big) {
      WdB = (unsigned short*)((char*)d_ws + need_small);
      cvt_wd_bf16<<<((size_t)DS * DM) / (4 * 256), 256, 0, stream>>>(W_dec, WdB);
    }
    transpose_w<<<dim3(DS / 32, DM / 32), 256, 0, stream>>>(W_enc, WTf, WTb);
    sae_encode_bf16<<<dim3(DS / 128, NROWS / 128), 256, 0, stream>>>(
        xb, WTb, b_enc, (unsigned short*)z, z);
    sae_topk_fused<<<NROWS, 256, 0, stream>>>(z, recon, x, WTf, b_enc,
                                              W_dec, WdB, b_dec, kp);
  } else {
    sae_encode_gemm<<<dim3(DS / BN, NROWS / BM), 256, 0, stream>>>(x, W_enc, b_enc, z);
    sae_topk_decode<<<NROWS, 256, 0, stream>>>(z, recon, W_dec, b_dec, kp);
  }
}